// Round 1
// baseline (749.378 us; speedup 1.0000x reference)
//
#include <hip/hip_runtime.h>

#define NN 50000
#define NE 500000
#define D  128
#define OD 64
#define NG 512

// ---------------- graph preprocessing (once per call) ----------------

__global__ void k_deg_init(float* deg) {
    int i = blockIdx.x * blockDim.x + threadIdx.x;
    if (i < NN) deg[i] = 1.0f;   // self-loop weight 1
}

__global__ void k_deg_count(const int* __restrict__ col, const float* __restrict__ ew,
                            float* __restrict__ deg, int* __restrict__ counts) {
    int e = blockIdx.x * blockDim.x + threadIdx.x;
    if (e < NE) {
        int c = col[e];
        atomicAdd(&deg[c], ew[e]);
        atomicAdd(&counts[c], 1);
    }
}

__global__ void k_dinv(const float* __restrict__ deg, float* __restrict__ dinv,
                       float* __restrict__ selfc) {
    int i = blockIdx.x * blockDim.x + threadIdx.x;
    if (i < NN) {
        float r = rsqrtf(deg[i]);   // deg >= 1 always
        dinv[i] = r;
        selfc[i] = r * r;
    }
}

__global__ void k_norm(const int* __restrict__ row, const int* __restrict__ col,
                       const float* __restrict__ ew, const float* __restrict__ dinv,
                       float* __restrict__ normv) {
    int e = blockIdx.x * blockDim.x + threadIdx.x;
    if (e < NE) normv[e] = dinv[row[e]] * ew[e] * dinv[col[e]];
}

// single-block exclusive scan of counts[NN] -> offs[NN+1]
__global__ void k_scan(const int* __restrict__ counts, int* __restrict__ offs) {
    __shared__ int part[256];
    const int CH = 196;                 // 256*196 = 50176 >= 50000
    int t = threadIdx.x;
    int s = t * CH, e = min(s + CH, NN);
    int sum = 0;
    for (int i = s; i < e; ++i) sum += counts[i];
    part[t] = sum;
    __syncthreads();
    for (int st = 1; st < 256; st <<= 1) {
        int v = (t >= st) ? part[t - st] : 0;
        __syncthreads();
        part[t] += v;
        __syncthreads();
    }
    int run = part[t] - sum;            // exclusive base
    for (int i = s; i < e; ++i) { offs[i] = run; run += counts[i]; }
    if (t == 255) offs[NN] = part[255];
}

__global__ void k_fill(const int* __restrict__ row, const int* __restrict__ col,
                       const float* __restrict__ normv, const int* __restrict__ offs,
                       int* __restrict__ cursor, int* __restrict__ srow,
                       float* __restrict__ snorm) {
    int e = blockIdx.x * blockDim.x + threadIdx.x;
    if (e < NE) {
        int c = col[e];
        int p = offs[c] + atomicAdd(&cursor[c], 1);
        srow[p] = row[e];
        snorm[p] = normv[e];
    }
}

// ---------------- per-layer kernels ----------------

// H = X @ W ; W(128x128 fp32) staged in LDS, 256 rows per block.
// Each wave processes 2 rows at a time: lanes 0-31 row A, 32-63 row B,
// lane computes 4 consecutive output cols via float4 LDS reads.
__global__ __launch_bounds__(256) void k_gemm(const float* __restrict__ X,
                                              const float* __restrict__ W,
                                              float* __restrict__ H) {
    __shared__ float Ws[D * D];
    int t = threadIdx.x;
    for (int i = t; i < D * D; i += 256) Ws[i] = W[i];
    __syncthreads();
    int wave = t >> 6, lane = t & 63;
    int half = lane >> 5;
    int cl = (lane & 31) * 4;
    int rbase = blockIdx.x * 256;
    for (int i = 0; i < 32; ++i) {
        int r = rbase + 2 * (wave + 4 * i) + half;
        if (r < NN) {
            const float* xr = X + (size_t)r * D;
            float4 a = make_float4(0.f, 0.f, 0.f, 0.f);
            for (int k = 0; k < D; k += 4) {
                float4 xv = *(const float4*)(xr + k);
                float4 w0 = *(const float4*)(&Ws[(k + 0) * D + cl]);
                float4 w1 = *(const float4*)(&Ws[(k + 1) * D + cl]);
                float4 w2 = *(const float4*)(&Ws[(k + 2) * D + cl]);
                float4 w3 = *(const float4*)(&Ws[(k + 3) * D + cl]);
                a.x += xv.x * w0.x + xv.y * w1.x + xv.z * w2.x + xv.w * w3.x;
                a.y += xv.x * w0.y + xv.y * w1.y + xv.z * w2.y + xv.w * w3.y;
                a.z += xv.x * w0.z + xv.y * w1.z + xv.z * w2.z + xv.w * w3.z;
                a.w += xv.x * w0.w + xv.y * w1.w + xv.z * w2.w + xv.w * w3.w;
            }
            *(float4*)(&H[(size_t)r * D + cl]) = a;
        }
    }
}

// out[c] = selfc[c]*H[c] + sum_{j in CSR[c]} snorm[j]*H[srow[j]] + bias ; optional relu
__global__ __launch_bounds__(128) void k_agg(const float* __restrict__ Hm,
                                             const int* __restrict__ offs,
                                             const int* __restrict__ srow,
                                             const float* __restrict__ snorm,
                                             const float* __restrict__ selfc,
                                             const float* __restrict__ bias,
                                             float* __restrict__ out, int relu) {
    int c = blockIdx.x;
    int t = threadIdx.x;
    float acc = selfc[c] * Hm[(size_t)c * D + t];
    int s = offs[c], e = offs[c + 1];
    for (int j = s; j < e; ++j) {
        acc += snorm[j] * Hm[(size_t)srow[j] * D + t];
    }
    acc += bias[t];
    if (relu) acc = fmaxf(acc, 0.0f);
    out[(size_t)c * D + t] = acc;
}

// ---------------- pooling + FC ----------------

#define PCH 128
__global__ __launch_bounds__(128) void k_pool(const float* __restrict__ Hm,
                                              const int* __restrict__ batch,
                                              float* __restrict__ psum,
                                              float* __restrict__ pcnt) {
    int t = threadIdx.x;
    int s = blockIdx.x * PCH;
    int e = min(s + PCH, NN);
    if (s >= NN) return;
    float acc = 0.f;
    int cur = batch[s];
    int cnt = 0;
    for (int n = s; n < e; ++n) {
        int g = batch[n];
        if (g != cur) {
            atomicAdd(&psum[cur * D + t], acc);
            if (t == 0) atomicAdd(&pcnt[cur], (float)cnt);
            acc = 0.f; cnt = 0; cur = g;
        }
        acc += Hm[(size_t)n * D + t];
        cnt++;
    }
    atomicAdd(&psum[cur * D + t], acc);
    if (t == 0) atomicAdd(&pcnt[cur], (float)cnt);
}

__global__ __launch_bounds__(64) void k_fc(const float* __restrict__ psum,
                                           const float* __restrict__ pcnt,
                                           const float* __restrict__ Wfc,
                                           const float* __restrict__ bfc,
                                           float* __restrict__ outp) {
    __shared__ float prow[D];
    int g = blockIdx.x, t = threadIdx.x;
    float inv = 1.0f / fmaxf(pcnt[g], 1.0f);
    prow[t]      = psum[g * D + t] * inv;
    prow[t + 64] = psum[g * D + t + 64] * inv;
    __syncthreads();
    float acc = bfc[t];
    for (int k = 0; k < D; ++k) acc += prow[k] * Wfc[k * OD + t];
    outp[g * OD + t] = acc;
}

// ---------------- launch ----------------

extern "C" void kernel_launch(void* const* d_in, const int* in_sizes, int n_in,
                              void* d_out, int out_size, void* d_ws, size_t ws_size,
                              hipStream_t stream) {
    const float* x    = (const float*)d_in[0];
    const int*   ei   = (const int*)d_in[1];
    const int*   row  = ei;
    const int*   col  = ei + NE;
    const float* ew   = (const float*)d_in[2];
    const int*   batch= (const int*)d_in[3];
    const float* W1 = (const float*)d_in[4];  const float* b1 = (const float*)d_in[5];
    const float* W2 = (const float*)d_in[6];  const float* b2 = (const float*)d_in[7];
    const float* W3 = (const float*)d_in[8];  const float* b3 = (const float*)d_in[9];
    const float* W4 = (const float*)d_in[10]; const float* b4 = (const float*)d_in[11];
    const float* Wfc= (const float*)d_in[12]; const float* bfc= (const float*)d_in[13];

    float* ws = (float*)d_ws;
    float* deg    = ws + 0;
    float* dinv   = ws + 50048;
    float* selfc  = ws + 100096;
    float* normv  = ws + 150144;
    int*   counts = (int*)(ws + 650176);
    int*   offs   = (int*)(ws + 700224);
    int*   cursor = (int*)(ws + 750272);
    int*   srow   = (int*)(ws + 800320);
    float* snorm  = ws + 1300352;
    float* h      = ws + 1800384;
    float* bufA   = ws + 8200384;
    float* bufB   = ws + 14600384;
    float* psum   = ws + 21000384;
    float* pcnt   = ws + 21065920;

    const int TB = 256;
    int nblk = (NN + TB - 1) / TB;   // 196
    int eblk = (NE + TB - 1) / TB;   // 1954

    // preprocessing
    hipMemsetAsync(counts, 0, NN * sizeof(int), stream);
    hipMemsetAsync(cursor, 0, NN * sizeof(int), stream);
    hipMemsetAsync(psum, 0, NG * D * sizeof(float), stream);
    hipMemsetAsync(pcnt, 0, NG * sizeof(float), stream);
    k_deg_init<<<nblk, TB, 0, stream>>>(deg);
    k_deg_count<<<eblk, TB, 0, stream>>>(col, ew, deg, counts);
    k_dinv<<<nblk, TB, 0, stream>>>(deg, dinv, selfc);
    k_norm<<<eblk, TB, 0, stream>>>(row, col, ew, dinv, normv);
    k_scan<<<1, 256, 0, stream>>>(counts, offs);
    k_fill<<<eblk, TB, 0, stream>>>(row, col, normv, offs, cursor, srow, snorm);

    // 4 GCN layers
    k_gemm<<<196, 256, 0, stream>>>(x, W1, h);
    k_agg<<<NN, 128, 0, stream>>>(h, offs, srow, snorm, selfc, b1, bufA, 1);
    k_gemm<<<196, 256, 0, stream>>>(bufA, W2, h);
    k_agg<<<NN, 128, 0, stream>>>(h, offs, srow, snorm, selfc, b2, bufB, 1);
    k_gemm<<<196, 256, 0, stream>>>(bufB, W3, h);
    k_agg<<<NN, 128, 0, stream>>>(h, offs, srow, snorm, selfc, b3, bufA, 1);
    k_gemm<<<196, 256, 0, stream>>>(bufA, W4, h);
    k_agg<<<NN, 128, 0, stream>>>(h, offs, srow, snorm, selfc, b4, bufB, 0);

    // pool + fc
    k_pool<<<(NN + PCH - 1) / PCH, 128, 0, stream>>>(bufB, batch, psum, pcnt);
    k_fc<<<NG, 64, 0, stream>>>(psum, pcnt, Wfc, bfc, (float*)d_out);
}

// Round 2
// 648.905 us; speedup vs baseline: 1.1548x; 1.1548x over previous
//
#include <hip/hip_runtime.h>

#define NN 50000
#define NE 500000
#define D  128
#define OD 64
#define NG 512

// ---------------- graph preprocessing (once per call) ----------------

__global__ void k_deg_init(float* deg) {
    int i = blockIdx.x * blockDim.x + threadIdx.x;
    if (i < NN) deg[i] = 1.0f;   // self-loop weight 1
}

__global__ void k_deg_count(const int* __restrict__ col, const float* __restrict__ ew,
                            float* __restrict__ deg, int* __restrict__ counts) {
    int e = blockIdx.x * blockDim.x + threadIdx.x;
    if (e < NE) {
        int c = col[e];
        atomicAdd(&deg[c], ew[e]);
        atomicAdd(&counts[c], 1);
    }
}

__global__ void k_dinv(const float* __restrict__ deg, float* __restrict__ dinv,
                       float* __restrict__ selfc) {
    int i = blockIdx.x * blockDim.x + threadIdx.x;
    if (i < NN) {
        float r = rsqrtf(deg[i]);   // deg >= 1 always
        dinv[i] = r;
        selfc[i] = r * r;
    }
}

__global__ void k_norm(const int* __restrict__ row, const int* __restrict__ col,
                       const float* __restrict__ ew, const float* __restrict__ dinv,
                       float* __restrict__ normv) {
    int e = blockIdx.x * blockDim.x + threadIdx.x;
    if (e < NE) normv[e] = dinv[row[e]] * ew[e] * dinv[col[e]];
}

// single-block exclusive scan of counts[NN] -> offs[NN+1]
__global__ void k_scan(const int* __restrict__ counts, int* __restrict__ offs) {
    __shared__ int part[256];
    const int CH = 196;                 // 256*196 = 50176 >= 50000
    int t = threadIdx.x;
    int s = t * CH, e = min(s + CH, NN);
    int sum = 0;
    for (int i = s; i < e; ++i) sum += counts[i];
    part[t] = sum;
    __syncthreads();
    for (int st = 1; st < 256; st <<= 1) {
        int v = (t >= st) ? part[t - st] : 0;
        __syncthreads();
        part[t] += v;
        __syncthreads();
    }
    int run = part[t] - sum;            // exclusive base
    for (int i = s; i < e; ++i) { offs[i] = run; run += counts[i]; }
    if (t == 255) offs[NN] = part[255];
}

__global__ void k_fill(const int* __restrict__ row, const int* __restrict__ col,
                       const float* __restrict__ normv, const int* __restrict__ offs,
                       int* __restrict__ cursor, int* __restrict__ srow,
                       float* __restrict__ snorm) {
    int e = blockIdx.x * blockDim.x + threadIdx.x;
    if (e < NE) {
        int c = col[e];
        int p = offs[c] + atomicAdd(&cursor[c], 1);
        srow[p] = row[e];
        snorm[p] = normv[e];
    }
}

// ---------------- per-layer kernels ----------------

// H = X @ W. W (128x128 fp32, 64 KB) staged in LDS once per block.
// Register blocking: each lane owns 4 rows x 4 cols -> the 4 W ds_read_b128
// per K-step feed 64 FMAs (0.5 B/FLOP; VALU-bound, not LDS-bound).
// Block = 256 threads covers 64 rows in 2 passes of 32; grid = 782.
__global__ __launch_bounds__(256) void k_gemm(const float* __restrict__ X,
                                              const float* __restrict__ W,
                                              float* __restrict__ H) {
    __shared__ float Ws[D * D];
    int t = threadIdx.x;
    for (int i = t; i < D * D / 4; i += 256)
        ((float4*)Ws)[i] = ((const float4*)W)[i];
    __syncthreads();
    int wave = t >> 6, lane = t & 63;
    int half = lane >> 5;
    int cl = (lane & 31) * 4;            // output col base
    int rblk = blockIdx.x * 64;
    #pragma unroll
    for (int p = 0; p < 2; ++p) {
        int r0 = rblk + p * 32 + wave * 8 + half * 4;
        if (r0 + 3 < NN) {
            const float* x0 = X + (size_t)r0 * D;
            float4 a0 = {0,0,0,0}, a1 = {0,0,0,0}, a2 = {0,0,0,0}, a3 = {0,0,0,0};
            #pragma unroll 4
            for (int k = 0; k < D; k += 4) {
                float4 w0 = *(const float4*)(&Ws[(k + 0) * D + cl]);
                float4 w1 = *(const float4*)(&Ws[(k + 1) * D + cl]);
                float4 w2 = *(const float4*)(&Ws[(k + 2) * D + cl]);
                float4 w3 = *(const float4*)(&Ws[(k + 3) * D + cl]);
                float4 x0v = *(const float4*)(x0 + 0 * D + k);
                float4 x1v = *(const float4*)(x0 + 1 * D + k);
                float4 x2v = *(const float4*)(x0 + 2 * D + k);
                float4 x3v = *(const float4*)(x0 + 3 * D + k);
                a0.x += x0v.x*w0.x + x0v.y*w1.x + x0v.z*w2.x + x0v.w*w3.x;
                a0.y += x0v.x*w0.y + x0v.y*w1.y + x0v.z*w2.y + x0v.w*w3.y;
                a0.z += x0v.x*w0.z + x0v.y*w1.z + x0v.z*w2.z + x0v.w*w3.z;
                a0.w += x0v.x*w0.w + x0v.y*w1.w + x0v.z*w2.w + x0v.w*w3.w;
                a1.x += x1v.x*w0.x + x1v.y*w1.x + x1v.z*w2.x + x1v.w*w3.x;
                a1.y += x1v.x*w0.y + x1v.y*w1.y + x1v.z*w2.y + x1v.w*w3.y;
                a1.z += x1v.x*w0.z + x1v.y*w1.z + x1v.z*w2.z + x1v.w*w3.z;
                a1.w += x1v.x*w0.w + x1v.y*w1.w + x1v.z*w2.w + x1v.w*w3.w;
                a2.x += x2v.x*w0.x + x2v.y*w1.x + x2v.z*w2.x + x2v.w*w3.x;
                a2.y += x2v.x*w0.y + x2v.y*w1.y + x2v.z*w2.y + x2v.w*w3.y;
                a2.z += x2v.x*w0.z + x2v.y*w1.z + x2v.z*w2.z + x2v.w*w3.z;
                a2.w += x2v.x*w0.w + x2v.y*w1.w + x2v.z*w2.w + x2v.w*w3.w;
                a3.x += x3v.x*w0.x + x3v.y*w1.x + x3v.z*w2.x + x3v.w*w3.x;
                a3.y += x3v.x*w0.y + x3v.y*w1.y + x3v.z*w2.y + x3v.w*w3.y;
                a3.z += x3v.x*w0.z + x3v.y*w1.z + x3v.z*w2.z + x3v.w*w3.z;
                a3.w += x3v.x*w0.w + x3v.y*w1.w + x3v.z*w2.w + x3v.w*w3.w;
            }
            *(float4*)(&H[(size_t)(r0 + 0) * D + cl]) = a0;
            *(float4*)(&H[(size_t)(r0 + 1) * D + cl]) = a1;
            *(float4*)(&H[(size_t)(r0 + 2) * D + cl]) = a2;
            *(float4*)(&H[(size_t)(r0 + 3) * D + cl]) = a3;
        } else {
            for (int rr = 0; rr < 4; ++rr) {
                int r = r0 + rr;
                if (r >= NN) break;
                const float* xr = X + (size_t)r * D;
                float4 a = {0,0,0,0};
                for (int k = 0; k < D; k += 4) {
                    float4 xv = *(const float4*)(xr + k);
                    float4 w0 = *(const float4*)(&Ws[(k + 0) * D + cl]);
                    float4 w1 = *(const float4*)(&Ws[(k + 1) * D + cl]);
                    float4 w2 = *(const float4*)(&Ws[(k + 2) * D + cl]);
                    float4 w3 = *(const float4*)(&Ws[(k + 3) * D + cl]);
                    a.x += xv.x*w0.x + xv.y*w1.x + xv.z*w2.x + xv.w*w3.x;
                    a.y += xv.x*w0.y + xv.y*w1.y + xv.z*w2.y + xv.w*w3.y;
                    a.z += xv.x*w0.z + xv.y*w1.z + xv.z*w2.z + xv.w*w3.z;
                    a.w += xv.x*w0.w + xv.y*w1.w + xv.z*w2.w + xv.w*w3.w;
                }
                *(float4*)(&H[(size_t)r * D + cl]) = a;
            }
        }
    }
}

// out[c] = selfc[c]*H[c] + sum_{j in CSR[c]} snorm[j]*H[srow[j]] + bias ; optional relu
// half-wave (32 lanes) per node, float4 per lane; 8 nodes per 256-thread block.
__global__ __launch_bounds__(256) void k_agg(const float* __restrict__ Hm,
                                             const int* __restrict__ offs,
                                             const int* __restrict__ srow,
                                             const float* __restrict__ snorm,
                                             const float* __restrict__ selfc,
                                             const float* __restrict__ bias,
                                             float* __restrict__ out, int relu) {
    int node = blockIdx.x * 8 + (threadIdx.x >> 5);
    if (node >= NN) return;
    int l4 = (threadIdx.x & 31) * 4;
    float4 acc = *(const float4*)(&Hm[(size_t)node * D + l4]);
    float sc = selfc[node];
    acc.x *= sc; acc.y *= sc; acc.z *= sc; acc.w *= sc;
    int s = offs[node], e = offs[node + 1];
    for (int j = s; j < e; ++j) {
        float w = snorm[j];
        float4 v = *(const float4*)(&Hm[(size_t)srow[j] * D + l4]);
        acc.x += w * v.x; acc.y += w * v.y; acc.z += w * v.z; acc.w += w * v.w;
    }
    float4 b = *(const float4*)(&bias[l4]);
    acc.x += b.x; acc.y += b.y; acc.z += b.z; acc.w += b.w;
    if (relu) {
        acc.x = fmaxf(acc.x, 0.f); acc.y = fmaxf(acc.y, 0.f);
        acc.z = fmaxf(acc.z, 0.f); acc.w = fmaxf(acc.w, 0.f);
    }
    *(float4*)(&out[(size_t)node * D + l4]) = acc;
}

// ---------------- pooling + FC ----------------

#define PCH 128
__global__ __launch_bounds__(128) void k_pool(const float* __restrict__ Hm,
                                              const int* __restrict__ batch,
                                              float* __restrict__ psum,
                                              float* __restrict__ pcnt) {
    int t = threadIdx.x;
    int s = blockIdx.x * PCH;
    int e = min(s + PCH, NN);
    if (s >= NN) return;
    float acc = 0.f;
    int cur = batch[s];
    int cnt = 0;
    for (int n = s; n < e; ++n) {
        int g = batch[n];
        if (g != cur) {
            atomicAdd(&psum[cur * D + t], acc);
            if (t == 0) atomicAdd(&pcnt[cur], (float)cnt);
            acc = 0.f; cnt = 0; cur = g;
        }
        acc += Hm[(size_t)n * D + t];
        cnt++;
    }
    atomicAdd(&psum[cur * D + t], acc);
    if (t == 0) atomicAdd(&pcnt[cur], (float)cnt);
}

__global__ __launch_bounds__(64) void k_fc(const float* __restrict__ psum,
                                           const float* __restrict__ pcnt,
                                           const float* __restrict__ Wfc,
                                           const float* __restrict__ bfc,
                                           float* __restrict__ outp) {
    __shared__ float prow[D];
    int g = blockIdx.x, t = threadIdx.x;
    float inv = 1.0f / fmaxf(pcnt[g], 1.0f);
    prow[t]      = psum[g * D + t] * inv;
    prow[t + 64] = psum[g * D + t + 64] * inv;
    __syncthreads();
    float acc = bfc[t];
    for (int k = 0; k < D; ++k) acc += prow[k] * Wfc[k * OD + t];
    outp[g * OD + t] = acc;
}

// ---------------- launch ----------------

extern "C" void kernel_launch(void* const* d_in, const int* in_sizes, int n_in,
                              void* d_out, int out_size, void* d_ws, size_t ws_size,
                              hipStream_t stream) {
    const float* x    = (const float*)d_in[0];
    const int*   ei   = (const int*)d_in[1];
    const int*   row  = ei;
    const int*   col  = ei + NE;
    const float* ew   = (const float*)d_in[2];
    const int*   batch= (const int*)d_in[3];
    const float* W1 = (const float*)d_in[4];  const float* b1 = (const float*)d_in[5];
    const float* W2 = (const float*)d_in[6];  const float* b2 = (const float*)d_in[7];
    const float* W3 = (const float*)d_in[8];  const float* b3 = (const float*)d_in[9];
    const float* W4 = (const float*)d_in[10]; const float* b4 = (const float*)d_in[11];
    const float* Wfc= (const float*)d_in[12]; const float* bfc= (const float*)d_in[13];

    float* ws = (float*)d_ws;
    float* deg    = ws + 0;
    float* dinv   = ws + 50048;
    float* selfc  = ws + 100096;
    float* normv  = ws + 150144;
    int*   counts = (int*)(ws + 650176);
    int*   offs   = (int*)(ws + 700224);
    int*   cursor = (int*)(ws + 750272);
    int*   srow   = (int*)(ws + 800320);
    float* snorm  = ws + 1300352;
    float* h      = ws + 1800384;
    float* bufA   = ws + 8200384;
    float* bufB   = ws + 14600384;
    float* psum   = ws + 21000384;
    float* pcnt   = ws + 21065920;

    const int TB = 256;
    int nblk = (NN + TB - 1) / TB;   // 196
    int eblk = (NE + TB - 1) / TB;   // 1954

    // preprocessing
    hipMemsetAsync(counts, 0, NN * sizeof(int), stream);
    hipMemsetAsync(cursor, 0, NN * sizeof(int), stream);
    hipMemsetAsync(psum, 0, NG * D * sizeof(float), stream);
    hipMemsetAsync(pcnt, 0, NG * sizeof(float), stream);
    k_deg_init<<<nblk, TB, 0, stream>>>(deg);
    k_deg_count<<<eblk, TB, 0, stream>>>(col, ew, deg, counts);
    k_dinv<<<nblk, TB, 0, stream>>>(deg, dinv, selfc);
    k_norm<<<eblk, TB, 0, stream>>>(row, col, ew, dinv, normv);
    k_scan<<<1, 256, 0, stream>>>(counts, offs);
    k_fill<<<eblk, TB, 0, stream>>>(row, col, normv, offs, cursor, srow, snorm);

    const int GB = (NN + 63) / 64;       // 782 gemm blocks
    const int AB = (NN + 7) / 8;         // 6250 agg blocks

    // 4 GCN layers
    k_gemm<<<GB, 256, 0, stream>>>(x, W1, h);
    k_agg<<<AB, 256, 0, stream>>>(h, offs, srow, snorm, selfc, b1, bufA, 1);
    k_gemm<<<GB, 256, 0, stream>>>(bufA, W2, h);
    k_agg<<<AB, 256, 0, stream>>>(h, offs, srow, snorm, selfc, b2, bufB, 1);
    k_gemm<<<GB, 256, 0, stream>>>(bufB, W3, h);
    k_agg<<<AB, 256, 0, stream>>>(h, offs, srow, snorm, selfc, b3, bufA, 1);
    k_gemm<<<GB, 256, 0, stream>>>(bufA, W4, h);
    k_agg<<<AB, 256, 0, stream>>>(h, offs, srow, snorm, selfc, b4, bufB, 0);

    // pool + fc
    k_pool<<<(NN + PCH - 1) / PCH, 128, 0, stream>>>(bufB, batch, psum, pcnt);
    k_fc<<<NG, 64, 0, stream>>>(psum, pcnt, Wfc, bfc, (float*)d_out);
}

// Round 3
// 572.910 us; speedup vs baseline: 1.3080x; 1.1326x over previous
//
#include <hip/hip_runtime.h>

#define NN 50000
#define NE 500000
#define D  128
#define OD 64
#define NG 512

// ---------------- graph preprocessing (once per call) ----------------

__global__ void k_deg_init(float* deg) {
    int i = blockIdx.x * blockDim.x + threadIdx.x;
    if (i < NN) deg[i] = 1.0f;   // self-loop weight 1
}

__global__ void k_deg_count(const int* __restrict__ col, const float* __restrict__ ew,
                            float* __restrict__ deg, int* __restrict__ counts) {
    int e = blockIdx.x * blockDim.x + threadIdx.x;
    if (e < NE) {
        int c = col[e];
        atomicAdd(&deg[c], ew[e]);
        atomicAdd(&counts[c], 1);
    }
}

__global__ void k_dinv(const float* __restrict__ deg, float* __restrict__ dinv,
                       float* __restrict__ selfc) {
    int i = blockIdx.x * blockDim.x + threadIdx.x;
    if (i < NN) {
        float r = rsqrtf(deg[i]);   // deg >= 1 always
        dinv[i] = r;
        selfc[i] = r * r;
    }
}

__global__ void k_norm(const int* __restrict__ row, const int* __restrict__ col,
                       const float* __restrict__ ew, const float* __restrict__ dinv,
                       float* __restrict__ normv) {
    int e = blockIdx.x * blockDim.x + threadIdx.x;
    if (e < NE) normv[e] = dinv[row[e]] * ew[e] * dinv[col[e]];
}

// ---- 3-level parallel exclusive scan of counts[NN] -> offs[NN+1] ----
// level 1: per-block (256 elems) LDS scan + block total
__global__ __launch_bounds__(256) void k_scan_blk(const int* __restrict__ counts,
                                                  int* __restrict__ offs,
                                                  int* __restrict__ bsum) {
    __shared__ int tmp[256];
    int b = blockIdx.x, t = threadIdx.x;
    int i = b * 256 + t;
    int v = (i < NN) ? counts[i] : 0;
    tmp[t] = v;
    __syncthreads();
    for (int st = 1; st < 256; st <<= 1) {
        int u = (t >= st) ? tmp[t - st] : 0;
        __syncthreads();
        tmp[t] += u;
        __syncthreads();
    }
    if (i < NN) offs[i] = tmp[t] - v;        // exclusive within block
    if (t == 255) bsum[b] = tmp[255];
}

// level 2: scan the 196 block totals (one tiny block)
__global__ __launch_bounds__(256) void k_scan_top(const int* __restrict__ bsum,
                                                  int* __restrict__ bbase, int nb) {
    __shared__ int tmp[256];
    int t = threadIdx.x;
    int v = (t < nb) ? bsum[t] : 0;
    tmp[t] = v;
    __syncthreads();
    for (int st = 1; st < 256; st <<= 1) {
        int u = (t >= st) ? tmp[t - st] : 0;
        __syncthreads();
        tmp[t] += u;
        __syncthreads();
    }
    if (t < nb) bbase[t] = tmp[t] - v;       // exclusive
}

// level 3: add block bases; offs[NN] = NE (total edge count is known)
__global__ __launch_bounds__(256) void k_scan_add(int* __restrict__ offs,
                                                  const int* __restrict__ bbase) {
    int b = blockIdx.x, t = threadIdx.x;
    int i = b * 256 + t;
    if (i < NN) offs[i] += bbase[b];
    if (b == 0 && t == 0) offs[NN] = NE;
}

__global__ void k_fill(const int* __restrict__ row, const int* __restrict__ col,
                       const float* __restrict__ normv, const int* __restrict__ offs,
                       int* __restrict__ cursor, int* __restrict__ srow,
                       float* __restrict__ snorm) {
    int e = blockIdx.x * blockDim.x + threadIdx.x;
    if (e < NE) {
        int c = col[e];
        int p = offs[c] + atomicAdd(&cursor[c], 1);
        srow[p] = row[e];
        snorm[p] = normv[e];
    }
}

// ---------------- per-layer kernels ----------------

// H = X @ W. W (128x128 fp32, 64 KB) staged in LDS once per block.
// Register blocking: each lane owns 4 rows x 4 cols -> the 4 W ds_read_b128
// per K-step feed 64 FMAs (0.5 B/FLOP; VALU-bound, not LDS-bound).
__global__ __launch_bounds__(256) void k_gemm(const float* __restrict__ X,
                                              const float* __restrict__ W,
                                              float* __restrict__ H) {
    __shared__ float Ws[D * D];
    int t = threadIdx.x;
    for (int i = t; i < D * D / 4; i += 256)
        ((float4*)Ws)[i] = ((const float4*)W)[i];
    __syncthreads();
    int wave = t >> 6, lane = t & 63;
    int half = lane >> 5;
    int cl = (lane & 31) * 4;            // output col base
    int rblk = blockIdx.x * 64;
    #pragma unroll
    for (int p = 0; p < 2; ++p) {
        int r0 = rblk + p * 32 + wave * 8 + half * 4;
        if (r0 + 3 < NN) {
            const float* x0 = X + (size_t)r0 * D;
            float4 a0 = {0,0,0,0}, a1 = {0,0,0,0}, a2 = {0,0,0,0}, a3 = {0,0,0,0};
            #pragma unroll 4
            for (int k = 0; k < D; k += 4) {
                float4 w0 = *(const float4*)(&Ws[(k + 0) * D + cl]);
                float4 w1 = *(const float4*)(&Ws[(k + 1) * D + cl]);
                float4 w2 = *(const float4*)(&Ws[(k + 2) * D + cl]);
                float4 w3 = *(const float4*)(&Ws[(k + 3) * D + cl]);
                float4 x0v = *(const float4*)(x0 + 0 * D + k);
                float4 x1v = *(const float4*)(x0 + 1 * D + k);
                float4 x2v = *(const float4*)(x0 + 2 * D + k);
                float4 x3v = *(const float4*)(x0 + 3 * D + k);
                a0.x += x0v.x*w0.x + x0v.y*w1.x + x0v.z*w2.x + x0v.w*w3.x;
                a0.y += x0v.x*w0.y + x0v.y*w1.y + x0v.z*w2.y + x0v.w*w3.y;
                a0.z += x0v.x*w0.z + x0v.y*w1.z + x0v.z*w2.z + x0v.w*w3.z;
                a0.w += x0v.x*w0.w + x0v.y*w1.w + x0v.z*w2.w + x0v.w*w3.w;
                a1.x += x1v.x*w0.x + x1v.y*w1.x + x1v.z*w2.x + x1v.w*w3.x;
                a1.y += x1v.x*w0.y + x1v.y*w1.y + x1v.z*w2.y + x1v.w*w3.y;
                a1.z += x1v.x*w0.z + x1v.y*w1.z + x1v.z*w2.z + x1v.w*w3.z;
                a1.w += x1v.x*w0.w + x1v.y*w1.w + x1v.z*w2.w + x1v.w*w3.w;
                a2.x += x2v.x*w0.x + x2v.y*w1.x + x2v.z*w2.x + x2v.w*w3.x;
                a2.y += x2v.x*w0.y + x2v.y*w1.y + x2v.z*w2.y + x2v.w*w3.y;
                a2.z += x2v.x*w0.z + x2v.y*w1.z + x2v.z*w2.z + x2v.w*w3.z;
                a2.w += x2v.x*w0.w + x2v.y*w1.w + x2v.z*w2.w + x2v.w*w3.w;
                a3.x += x3v.x*w0.x + x3v.y*w1.x + x3v.z*w2.x + x3v.w*w3.x;
                a3.y += x3v.x*w0.y + x3v.y*w1.y + x3v.z*w2.y + x3v.w*w3.y;
                a3.z += x3v.x*w0.z + x3v.y*w1.z + x3v.z*w2.z + x3v.w*w3.z;
                a3.w += x3v.x*w0.w + x3v.y*w1.w + x3v.z*w2.w + x3v.w*w3.w;
            }
            *(float4*)(&H[(size_t)(r0 + 0) * D + cl]) = a0;
            *(float4*)(&H[(size_t)(r0 + 1) * D + cl]) = a1;
            *(float4*)(&H[(size_t)(r0 + 2) * D + cl]) = a2;
            *(float4*)(&H[(size_t)(r0 + 3) * D + cl]) = a3;
        } else {
            for (int rr = 0; rr < 4; ++rr) {
                int r = r0 + rr;
                if (r >= NN) break;
                const float* xr = X + (size_t)r * D;
                float4 a = {0,0,0,0};
                for (int k = 0; k < D; k += 4) {
                    float4 xv = *(const float4*)(xr + k);
                    float4 w0 = *(const float4*)(&Ws[(k + 0) * D + cl]);
                    float4 w1 = *(const float4*)(&Ws[(k + 1) * D + cl]);
                    float4 w2 = *(const float4*)(&Ws[(k + 2) * D + cl]);
                    float4 w3 = *(const float4*)(&Ws[(k + 3) * D + cl]);
                    a.x += xv.x*w0.x + xv.y*w1.x + xv.z*w2.x + xv.w*w3.x;
                    a.y += xv.x*w0.y + xv.y*w1.y + xv.z*w2.y + xv.w*w3.y;
                    a.z += xv.x*w0.z + xv.y*w1.z + xv.z*w2.z + xv.w*w3.z;
                    a.w += xv.x*w0.w + xv.y*w1.w + xv.z*w2.w + xv.w*w3.w;
                }
                *(float4*)(&H[(size_t)r * D + cl]) = a;
            }
        }
    }
}

// out[c] = selfc[c]*H[c] + sum_{j in CSR[c]} snorm[j]*H[srow[j]] + bias ; optional relu
// half-wave (32 lanes) per node, float4 per lane; 8 nodes per 256-thread block.
__global__ __launch_bounds__(256) void k_agg(const float* __restrict__ Hm,
                                             const int* __restrict__ offs,
                                             const int* __restrict__ srow,
                                             const float* __restrict__ snorm,
                                             const float* __restrict__ selfc,
                                             const float* __restrict__ bias,
                                             float* __restrict__ out, int relu) {
    int node = blockIdx.x * 8 + (threadIdx.x >> 5);
    if (node >= NN) return;
    int l4 = (threadIdx.x & 31) * 4;
    float4 acc = *(const float4*)(&Hm[(size_t)node * D + l4]);
    float sc = selfc[node];
    acc.x *= sc; acc.y *= sc; acc.z *= sc; acc.w *= sc;
    int s = offs[node], e = offs[node + 1];
    for (int j = s; j < e; ++j) {
        float w = snorm[j];
        float4 v = *(const float4*)(&Hm[(size_t)srow[j] * D + l4]);
        acc.x += w * v.x; acc.y += w * v.y; acc.z += w * v.z; acc.w += w * v.w;
    }
    float4 b = *(const float4*)(&bias[l4]);
    acc.x += b.x; acc.y += b.y; acc.z += b.z; acc.w += b.w;
    if (relu) {
        acc.x = fmaxf(acc.x, 0.f); acc.y = fmaxf(acc.y, 0.f);
        acc.z = fmaxf(acc.z, 0.f); acc.w = fmaxf(acc.w, 0.f);
    }
    *(float4*)(&out[(size_t)node * D + l4]) = acc;
}

// ---------------- pooling + FC ----------------

#define PCH 128
__global__ __launch_bounds__(128) void k_pool(const float* __restrict__ Hm,
                                              const int* __restrict__ batch,
                                              float* __restrict__ psum,
                                              float* __restrict__ pcnt) {
    int t = threadIdx.x;
    int s = blockIdx.x * PCH;
    int e = min(s + PCH, NN);
    if (s >= NN) return;
    float acc = 0.f;
    int cur = batch[s];
    int cnt = 0;
    for (int n = s; n < e; ++n) {
        int g = batch[n];
        if (g != cur) {
            atomicAdd(&psum[cur * D + t], acc);
            if (t == 0) atomicAdd(&pcnt[cur], (float)cnt);
            acc = 0.f; cnt = 0; cur = g;
        }
        acc += Hm[(size_t)n * D + t];
        cnt++;
    }
    atomicAdd(&psum[cur * D + t], acc);
    if (t == 0) atomicAdd(&pcnt[cur], (float)cnt);
}

__global__ __launch_bounds__(64) void k_fc(const float* __restrict__ psum,
                                           const float* __restrict__ pcnt,
                                           const float* __restrict__ Wfc,
                                           const float* __restrict__ bfc,
                                           float* __restrict__ outp) {
    __shared__ float prow[D];
    int g = blockIdx.x, t = threadIdx.x;
    float inv = 1.0f / fmaxf(pcnt[g], 1.0f);
    prow[t]      = psum[g * D + t] * inv;
    prow[t + 64] = psum[g * D + t + 64] * inv;
    __syncthreads();
    float acc = bfc[t];
    for (int k = 0; k < D; ++k) acc += prow[k] * Wfc[k * OD + t];
    outp[g * OD + t] = acc;
}

// ---------------- launch ----------------

extern "C" void kernel_launch(void* const* d_in, const int* in_sizes, int n_in,
                              void* d_out, int out_size, void* d_ws, size_t ws_size,
                              hipStream_t stream) {
    const float* x    = (const float*)d_in[0];
    const int*   ei   = (const int*)d_in[1];
    const int*   row  = ei;
    const int*   col  = ei + NE;
    const float* ew   = (const float*)d_in[2];
    const int*   batch= (const int*)d_in[3];
    const float* W1 = (const float*)d_in[4];  const float* b1 = (const float*)d_in[5];
    const float* W2 = (const float*)d_in[6];  const float* b2 = (const float*)d_in[7];
    const float* W3 = (const float*)d_in[8];  const float* b3 = (const float*)d_in[9];
    const float* W4 = (const float*)d_in[10]; const float* b4 = (const float*)d_in[11];
    const float* Wfc= (const float*)d_in[12]; const float* bfc= (const float*)d_in[13];

    float* ws = (float*)d_ws;
    float* deg    = ws + 0;
    float* dinv   = ws + 50048;
    float* selfc  = ws + 100096;
    float* normv  = ws + 150144;
    int*   counts = (int*)(ws + 650176);
    int*   offs   = (int*)(ws + 700224);
    int*   cursor = (int*)(ws + 750272);
    int*   srow   = (int*)(ws + 800320);
    float* snorm  = ws + 1300352;
    float* h      = ws + 1800384;
    float* bufA   = ws + 8200384;
    float* bufB   = ws + 14600384;
    float* psum   = ws + 21000384;
    float* pcnt   = ws + 21065920;
    // deg is dead after k_dinv -> reuse its storage for scan temporaries
    int*   bsum   = (int*)deg;          // 196 block totals
    int*   bbase  = (int*)deg + 256;    // scanned bases

    const int TB = 256;
    int nblk = (NN + TB - 1) / TB;   // 196
    int eblk = (NE + TB - 1) / TB;   // 1954

    // preprocessing
    hipMemsetAsync(counts, 0, NN * sizeof(int), stream);
    hipMemsetAsync(cursor, 0, NN * sizeof(int), stream);
    hipMemsetAsync(psum, 0, NG * D * sizeof(float), stream);
    hipMemsetAsync(pcnt, 0, NG * sizeof(float), stream);
    k_deg_init<<<nblk, TB, 0, stream>>>(deg);
    k_deg_count<<<eblk, TB, 0, stream>>>(col, ew, deg, counts);
    k_dinv<<<nblk, TB, 0, stream>>>(deg, dinv, selfc);
    k_norm<<<eblk, TB, 0, stream>>>(row, col, ew, dinv, normv);
    k_scan_blk<<<nblk, 256, 0, stream>>>(counts, offs, bsum);
    k_scan_top<<<1, 256, 0, stream>>>(bsum, bbase, nblk);
    k_scan_add<<<nblk, 256, 0, stream>>>(offs, bbase);
    k_fill<<<eblk, TB, 0, stream>>>(row, col, normv, offs, cursor, srow, snorm);

    const int GB = (NN + 63) / 64;       // 782 gemm blocks
    const int AB = (NN + 7) / 8;         // 6250 agg blocks

    // 4 GCN layers
    k_gemm<<<GB, 256, 0, stream>>>(x, W1, h);
    k_agg<<<AB, 256, 0, stream>>>(h, offs, srow, snorm, selfc, b1, bufA, 1);
    k_gemm<<<GB, 256, 0, stream>>>(bufA, W2, h);
    k_agg<<<AB, 256, 0, stream>>>(h, offs, srow, snorm, selfc, b2, bufB, 1);
    k_gemm<<<GB, 256, 0, stream>>>(bufB, W3, h);
    k_agg<<<AB, 256, 0, stream>>>(h, offs, srow, snorm, selfc, b3, bufA, 1);
    k_gemm<<<GB, 256, 0, stream>>>(bufA, W4, h);
    k_agg<<<AB, 256, 0, stream>>>(h, offs, srow, snorm, selfc, b4, bufB, 0);

    // pool + fc
    k_pool<<<(NN + PCH - 1) / PCH, 128, 0, stream>>>(bufB, batch, psum, pcnt);
    k_fc<<<NG, 64, 0, stream>>>(psum, pcnt, Wfc, bfc, (float*)d_out);
}

// Round 4
// 397.265 us; speedup vs baseline: 1.8863x; 1.4421x over previous
//
#include <hip/hip_runtime.h>

#define NN 50000
#define NE 500000
#define D  128
#define OD 64
#define NG 512

typedef __attribute__((ext_vector_type(8))) short s8v;    // 8 bf16 (4 VGPR)
typedef __attribute__((ext_vector_type(4))) short s4v;    // 4 bf16 (8B)
typedef __attribute__((ext_vector_type(4))) float f4v;    // MFMA acc

__device__ inline unsigned short f2bf(float f) {
    unsigned u = __float_as_uint(f);
    unsigned r = (u + 0x7fffu + ((u >> 16) & 1u)) >> 16;   // RNE
    return (unsigned short)r;
}
__device__ inline float bf2f(unsigned short h) {
    return __uint_as_float(((unsigned)h) << 16);
}

// ---------------- graph preprocessing (once per call) ----------------

__global__ void k_deg_init(float* deg) {
    int i = blockIdx.x * blockDim.x + threadIdx.x;
    if (i < NN) deg[i] = 1.0f;   // self-loop weight 1
}

__global__ void k_deg_count(const int* __restrict__ col, const float* __restrict__ ew,
                            float* __restrict__ deg, int* __restrict__ counts) {
    int e = blockIdx.x * blockDim.x + threadIdx.x;
    if (e < NE) {
        int c = col[e];
        atomicAdd(&deg[c], ew[e]);
        atomicAdd(&counts[c], 1);
    }
}

__global__ void k_dinv(const float* __restrict__ deg, float* __restrict__ dinv,
                       float* __restrict__ selfc) {
    int i = blockIdx.x * blockDim.x + threadIdx.x;
    if (i < NN) {
        float r = rsqrtf(deg[i]);
        dinv[i] = r;
        selfc[i] = r * r;
    }
}

__global__ void k_norm(const int* __restrict__ row, const int* __restrict__ col,
                       const float* __restrict__ ew, const float* __restrict__ dinv,
                       float* __restrict__ normv) {
    int e = blockIdx.x * blockDim.x + threadIdx.x;
    if (e < NE) normv[e] = dinv[row[e]] * ew[e] * dinv[col[e]];
}

// ---- 3-level parallel exclusive scan of counts[NN] -> offs[NN+1] ----
__global__ __launch_bounds__(256) void k_scan_blk(const int* __restrict__ counts,
                                                  int* __restrict__ offs,
                                                  int* __restrict__ bsum) {
    __shared__ int tmp[256];
    int b = blockIdx.x, t = threadIdx.x;
    int i = b * 256 + t;
    int v = (i < NN) ? counts[i] : 0;
    tmp[t] = v;
    __syncthreads();
    for (int st = 1; st < 256; st <<= 1) {
        int u = (t >= st) ? tmp[t - st] : 0;
        __syncthreads();
        tmp[t] += u;
        __syncthreads();
    }
    if (i < NN) offs[i] = tmp[t] - v;
    if (t == 255) bsum[b] = tmp[255];
}

__global__ __launch_bounds__(256) void k_scan_top(const int* __restrict__ bsum,
                                                  int* __restrict__ bbase, int nb) {
    __shared__ int tmp[256];
    int t = threadIdx.x;
    int v = (t < nb) ? bsum[t] : 0;
    tmp[t] = v;
    __syncthreads();
    for (int st = 1; st < 256; st <<= 1) {
        int u = (t >= st) ? tmp[t - st] : 0;
        __syncthreads();
        tmp[t] += u;
        __syncthreads();
    }
    if (t < nb) bbase[t] = tmp[t] - v;
}

__global__ __launch_bounds__(256) void k_scan_add(int* __restrict__ offs,
                                                  const int* __restrict__ bbase) {
    int b = blockIdx.x, t = threadIdx.x;
    int i = b * 256 + t;
    if (i < NN) offs[i] += bbase[b];
    if (b == 0 && t == 0) offs[NN] = NE;
}

__global__ void k_fill(const int* __restrict__ row, const int* __restrict__ col,
                       const float* __restrict__ normv, const int* __restrict__ offs,
                       int* __restrict__ cursor, int* __restrict__ srow,
                       float* __restrict__ snorm) {
    int e = blockIdx.x * blockDim.x + threadIdx.x;
    if (e < NE) {
        int c = col[e];
        int p = offs[c] + atomicAdd(&cursor[c], 1);
        srow[p] = row[e];
        snorm[p] = normv[e];
    }
}

// ---------------- W packing into MFMA B-fragment layout ----------------
// B-frag for mfma_f32_16x16x32_bf16: lane holds B[k=(lane>>4)*8+j][n=lane&15].
// Packed index: (((nt*4 + s)*64 + lane)*8 + j); k = s*32+(lane>>4)*8+j, n = nt*16+(lane&15).
// grid 32 blocks: layer = bid>>3, 2048 elems per block.
__global__ __launch_bounds__(256) void k_pack_w(const float* __restrict__ w0,
                                                const float* __restrict__ w1,
                                                const float* __restrict__ w2,
                                                const float* __restrict__ w3,
                                                unsigned short* __restrict__ wpk) {
    int layer = blockIdx.x >> 3;
    int chunk = blockIdx.x & 7;
    const float* W = (layer == 0) ? w0 : (layer == 1) ? w1 : (layer == 2) ? w2 : w3;
    unsigned short* hi = wpk + layer * 32768;
    unsigned short* lo = hi + 16384;
    for (int it = 0; it < 8; ++it) {
        int p = chunk * 2048 + it * 256 + threadIdx.x;
        int j = p & 7, lane = (p >> 3) & 63, s = (p >> 9) & 3, nt = p >> 11;
        int k = s * 32 + ((lane >> 4) << 3) + j;
        int n = nt * 16 + (lane & 15);
        float v = W[k * D + n];
        unsigned short h = f2bf(v);
        hi[p] = h;
        lo[p] = f2bf(v - bf2f(h));
    }
}

// ---------------- MFMA GEMM: H = X @ W (split-bf16, 3 terms) ----------------
// Per wave: one 16-row tile, all 128 output cols (8 ntiles), K=128 (4 ksteps).
// A-frag: lane holds X[r0+(lane&15)][s*32+(lane>>4)*8 .. +8].
// C/D: col=lane&15, row=(lane>>4)*4+reg  [m89-verified].
template <int AFP32>
__global__ __launch_bounds__(256) void k_gemm_mfma(const float* __restrict__ Xf,
                                                   const unsigned short* __restrict__ Xhi,
                                                   const unsigned short* __restrict__ Xlo,
                                                   const unsigned short* __restrict__ Whi,
                                                   const unsigned short* __restrict__ Wlo,
                                                   float* __restrict__ H) {
    int wid = blockIdx.x * 4 + (threadIdx.x >> 6);
    if (wid >= NN / 16) return;                 // 3125 tiles, NN % 16 == 0
    int lane = threadIdx.x & 63;
    int r = wid * 16 + (lane & 15);             // A-row this lane serves
    int kg = (lane >> 4) << 3;                  // k-group base (0,8,16,24)

    s8v Ahi[4], Alo[4];
    if (AFP32) {
        const float* xr = Xf + (size_t)r * D + kg;
        #pragma unroll
        for (int s = 0; s < 4; ++s) {
            float4 va = *(const float4*)(xr + s * 32);
            float4 vb = *(const float4*)(xr + s * 32 + 4);
            float xv[8] = {va.x, va.y, va.z, va.w, vb.x, vb.y, vb.z, vb.w};
            #pragma unroll
            for (int j = 0; j < 8; ++j) {
                unsigned short h = f2bf(xv[j]);
                Ahi[s][j] = (short)h;
                Alo[s][j] = (short)f2bf(xv[j] - bf2f(h));
            }
        }
    } else {
        const unsigned short* xh = Xhi + (size_t)r * D + kg;
        const unsigned short* xl = Xlo + (size_t)r * D + kg;
        #pragma unroll
        for (int s = 0; s < 4; ++s) {
            Ahi[s] = *(const s8v*)(xh + s * 32);
            Alo[s] = *(const s8v*)(xl + s * 32);
        }
    }

    int cb = lane & 15;                          // C col within ntile
    int rb = wid * 16 + ((lane >> 4) << 2);      // C row base
    #pragma unroll
    for (int nt = 0; nt < 8; ++nt) {
        f4v acc = {0.f, 0.f, 0.f, 0.f};
        #pragma unroll
        for (int s = 0; s < 4; ++s) {
            int bi = ((nt * 4 + s) * 64 + lane) * 8;
            s8v bh = *(const s8v*)(Whi + bi);
            s8v bl = *(const s8v*)(Wlo + bi);
            acc = __builtin_amdgcn_mfma_f32_16x16x32_bf16(Ahi[s], bh, acc, 0, 0, 0);
            acc = __builtin_amdgcn_mfma_f32_16x16x32_bf16(Alo[s], bh, acc, 0, 0, 0);
            acc = __builtin_amdgcn_mfma_f32_16x16x32_bf16(Ahi[s], bl, acc, 0, 0, 0);
        }
        float* hp = H + (size_t)rb * D + nt * 16 + cb;
        hp[0 * D] = acc[0];
        hp[1 * D] = acc[1];
        hp[2 * D] = acc[2];
        hp[3 * D] = acc[3];
    }
}

// ---------------- aggregation ----------------
// out[c] = selfc[c]*H[c] + sum_{j in CSR[c]} snorm[j]*H[srow[j]] + bias ; optional relu.
// mode 1: relu + emit split bf16 hi/lo (feeds next MFMA GEMM).
// mode 0: emit fp32 (final layer, feeds pooling).
__global__ __launch_bounds__(256) void k_agg(const float* __restrict__ Hm,
                                             const int* __restrict__ offs,
                                             const int* __restrict__ srow,
                                             const float* __restrict__ snorm,
                                             const float* __restrict__ selfc,
                                             const float* __restrict__ bias,
                                             unsigned short* __restrict__ outHi,
                                             unsigned short* __restrict__ outLo,
                                             float* __restrict__ outF, int mode) {
    int node = blockIdx.x * 8 + (threadIdx.x >> 5);
    if (node >= NN) return;
    int l4 = (threadIdx.x & 31) * 4;
    float4 acc = *(const float4*)(&Hm[(size_t)node * D + l4]);
    float sc = selfc[node];
    acc.x *= sc; acc.y *= sc; acc.z *= sc; acc.w *= sc;
    int s = offs[node], e = offs[node + 1];
    for (int j = s; j < e; ++j) {
        float w = snorm[j];
        float4 v = *(const float4*)(&Hm[(size_t)srow[j] * D + l4]);
        acc.x += w * v.x; acc.y += w * v.y; acc.z += w * v.z; acc.w += w * v.w;
    }
    float4 b = *(const float4*)(&bias[l4]);
    acc.x += b.x; acc.y += b.y; acc.z += b.z; acc.w += b.w;
    if (mode) {
        acc.x = fmaxf(acc.x, 0.f); acc.y = fmaxf(acc.y, 0.f);
        acc.z = fmaxf(acc.z, 0.f); acc.w = fmaxf(acc.w, 0.f);
        float a[4] = {acc.x, acc.y, acc.z, acc.w};
        s4v hv, lv;
        #pragma unroll
        for (int q = 0; q < 4; ++q) {
            unsigned short h = f2bf(a[q]);
            hv[q] = (short)h;
            lv[q] = (short)f2bf(a[q] - bf2f(h));
        }
        *(s4v*)(outHi + (size_t)node * D + l4) = hv;
        *(s4v*)(outLo + (size_t)node * D + l4) = lv;
    } else {
        *(float4*)(&outF[(size_t)node * D + l4]) = acc;
    }
}

// ---------------- pooling + FC ----------------

#define PCH 128
__global__ __launch_bounds__(128) void k_pool(const float* __restrict__ Hm,
                                              const int* __restrict__ batch,
                                              float* __restrict__ psum,
                                              float* __restrict__ pcnt) {
    int t = threadIdx.x;
    int s = blockIdx.x * PCH;
    int e = min(s + PCH, NN);
    if (s >= NN) return;
    float acc = 0.f;
    int cur = batch[s];
    int cnt = 0;
    for (int n = s; n < e; ++n) {
        int g = batch[n];
        if (g != cur) {
            atomicAdd(&psum[cur * D + t], acc);
            if (t == 0) atomicAdd(&pcnt[cur], (float)cnt);
            acc = 0.f; cnt = 0; cur = g;
        }
        acc += Hm[(size_t)n * D + t];
        cnt++;
    }
    atomicAdd(&psum[cur * D + t], acc);
    if (t == 0) atomicAdd(&pcnt[cur], (float)cnt);
}

__global__ __launch_bounds__(64) void k_fc(const float* __restrict__ psum,
                                           const float* __restrict__ pcnt,
                                           const float* __restrict__ Wfc,
                                           const float* __restrict__ bfc,
                                           float* __restrict__ outp) {
    __shared__ float prow[D];
    int g = blockIdx.x, t = threadIdx.x;
    float inv = 1.0f / fmaxf(pcnt[g], 1.0f);
    prow[t]      = psum[g * D + t] * inv;
    prow[t + 64] = psum[g * D + t + 64] * inv;
    __syncthreads();
    float acc = bfc[t];
    for (int k = 0; k < D; ++k) acc += prow[k] * Wfc[k * OD + t];
    outp[g * OD + t] = acc;
}

// ---------------- launch ----------------

extern "C" void kernel_launch(void* const* d_in, const int* in_sizes, int n_in,
                              void* d_out, int out_size, void* d_ws, size_t ws_size,
                              hipStream_t stream) {
    const float* x    = (const float*)d_in[0];
    const int*   ei   = (const int*)d_in[1];
    const int*   row  = ei;
    const int*   col  = ei + NE;
    const float* ew   = (const float*)d_in[2];
    const int*   batch= (const int*)d_in[3];
    const float* W1 = (const float*)d_in[4];  const float* b1 = (const float*)d_in[5];
    const float* W2 = (const float*)d_in[6];  const float* b2 = (const float*)d_in[7];
    const float* W3 = (const float*)d_in[8];  const float* b3 = (const float*)d_in[9];
    const float* W4 = (const float*)d_in[10]; const float* b4 = (const float*)d_in[11];
    const float* Wfc= (const float*)d_in[12]; const float* bfc= (const float*)d_in[13];

    float* ws = (float*)d_ws;
    float* deg    = ws + 0;          // 50048
    float* dinv   = ws + 50048;
    float* selfc  = ws + 100096;
    float* normv  = ws + 150144;     // 500032
    int*   counts = (int*)(ws + 650176);
    int*   offs   = (int*)(ws + 700224);   // 50176
    int*   cursor = (int*)(ws + 750400);
    int*   srow   = (int*)(ws + 800448);
    float* snorm  = ws + 1300448;
    float* h      = ws + 1800448;          // 6.4M floats (gemm out)
    float* pair   = ws + 8200448;          // 6.4M floats: hi|lo bf16, or final fp32
    unsigned short* pairHi = (unsigned short*)pair;              // 6.4M bf16
    unsigned short* pairLo = pairHi + (size_t)NN * D;            // 6.4M bf16
    float* psum   = ws + 14600448;
    float* pcnt   = ws + 14665984;
    unsigned short* wpk = (unsigned short*)(ws + 14666496);      // 131072 ushort
    int*   bsum   = (int*)deg;       // deg dead after k_dinv
    int*   bbase  = (int*)deg + 256;

    const int TB = 256;
    int nblk = (NN + TB - 1) / TB;   // 196
    int eblk = (NE + TB - 1) / TB;   // 1954

    // preprocessing
    hipMemsetAsync(counts, 0, NN * sizeof(int), stream);
    hipMemsetAsync(cursor, 0, NN * sizeof(int), stream);
    hipMemsetAsync(psum, 0, NG * D * sizeof(float), stream);
    hipMemsetAsync(pcnt, 0, NG * sizeof(float), stream);
    k_pack_w<<<32, 256, 0, stream>>>(W1, W2, W3, W4, wpk);
    k_deg_init<<<nblk, TB, 0, stream>>>(deg);
    k_deg_count<<<eblk, TB, 0, stream>>>(col, ew, deg, counts);
    k_dinv<<<nblk, TB, 0, stream>>>(deg, dinv, selfc);
    k_norm<<<eblk, TB, 0, stream>>>(row, col, ew, dinv, normv);
    k_scan_blk<<<nblk, 256, 0, stream>>>(counts, offs, bsum);
    k_scan_top<<<1, 256, 0, stream>>>(bsum, bbase, nblk);
    k_scan_add<<<nblk, 256, 0, stream>>>(offs, bbase);
    k_fill<<<eblk, TB, 0, stream>>>(row, col, normv, offs, cursor, srow, snorm);

    const int GB = (NN / 16 + 3) / 4;    // 782 gemm blocks (4 waves each)
    const int AB = (NN + 7) / 8;         // 6250 agg blocks

    unsigned short* wh1 = wpk;               unsigned short* wl1 = wpk + 16384;
    unsigned short* wh2 = wpk + 32768;       unsigned short* wl2 = wpk + 49152;
    unsigned short* wh3 = wpk + 65536;       unsigned short* wl3 = wpk + 81920;
    unsigned short* wh4 = wpk + 98304;       unsigned short* wl4 = wpk + 114688;

    // 4 GCN layers
    k_gemm_mfma<1><<<GB, 256, 0, stream>>>(x, nullptr, nullptr, wh1, wl1, h);
    k_agg<<<AB, 256, 0, stream>>>(h, offs, srow, snorm, selfc, b1, pairHi, pairLo, nullptr, 1);
    k_gemm_mfma<0><<<GB, 256, 0, stream>>>(nullptr, pairHi, pairLo, wh2, wl2, h);
    k_agg<<<AB, 256, 0, stream>>>(h, offs, srow, snorm, selfc, b2, pairHi, pairLo, nullptr, 1);
    k_gemm_mfma<0><<<GB, 256, 0, stream>>>(nullptr, pairHi, pairLo, wh3, wl3, h);
    k_agg<<<AB, 256, 0, stream>>>(h, offs, srow, snorm, selfc, b3, pairHi, pairLo, nullptr, 1);
    k_gemm_mfma<0><<<GB, 256, 0, stream>>>(nullptr, pairHi, pairLo, wh4, wl4, h);
    k_agg<<<AB, 256, 0, stream>>>(h, offs, srow, snorm, selfc, b4, nullptr, nullptr, pair, 0);

    // pool + fc
    k_pool<<<(NN + PCH - 1) / PCH, 128, 0, stream>>>(pair, batch, psum, pcnt);
    k_fc<<<NG, 64, 0, stream>>>(psum, pcnt, Wfc, bfc, (float*)d_out);
}

// Round 5
// 364.208 us; speedup vs baseline: 2.0576x; 1.0908x over previous
//
#include <hip/hip_runtime.h>

#define NN 50000
#define NE 500000
#define D  128
#define OD 64
#define NG 512

typedef __attribute__((ext_vector_type(8))) short s8v;    // 8 bf16 (4 VGPR)
typedef __attribute__((ext_vector_type(4))) short s4v;    // 4 bf16 (8B)
typedef __attribute__((ext_vector_type(4))) float f4v;    // MFMA acc

__device__ inline unsigned short f2bf(float f) {
    unsigned u = __float_as_uint(f);
    unsigned r = (u + 0x7fffu + ((u >> 16) & 1u)) >> 16;   // RNE
    return (unsigned short)r;
}
__device__ inline float bf2f(unsigned short h) {
    return __uint_as_float(((unsigned)h) << 16);
}

// ---------------- CSR build (once per call) ----------------
// 1) one atomic per edge -> per-node count + this edge's arrival rank
__global__ void k_count_rank(const int* __restrict__ col,
                             int* __restrict__ counts, int* __restrict__ rank) {
    int e = blockIdx.x * blockDim.x + threadIdx.x;
    if (e < NE) rank[e] = atomicAdd(&counts[col[e]], 1);
}

// 2) 3-level parallel exclusive scan of counts[NN] -> offs[NN+1]
__global__ __launch_bounds__(256) void k_scan_blk(const int* __restrict__ counts,
                                                  int* __restrict__ offs,
                                                  int* __restrict__ bsum) {
    __shared__ int tmp[256];
    int b = blockIdx.x, t = threadIdx.x;
    int i = b * 256 + t;
    int v = (i < NN) ? counts[i] : 0;
    tmp[t] = v;
    __syncthreads();
    for (int st = 1; st < 256; st <<= 1) {
        int u = (t >= st) ? tmp[t - st] : 0;
        __syncthreads();
        tmp[t] += u;
        __syncthreads();
    }
    if (i < NN) offs[i] = tmp[t] - v;
    if (t == 255) bsum[b] = tmp[255];
}

__global__ __launch_bounds__(256) void k_scan_top(const int* __restrict__ bsum,
                                                  int* __restrict__ bbase, int nb) {
    __shared__ int tmp[256];
    int t = threadIdx.x;
    int v = (t < nb) ? bsum[t] : 0;
    tmp[t] = v;
    __syncthreads();
    for (int st = 1; st < 256; st <<= 1) {
        int u = (t >= st) ? tmp[t - st] : 0;
        __syncthreads();
        tmp[t] += u;
        __syncthreads();
    }
    if (t < nb) bbase[t] = tmp[t] - v;
}

__global__ __launch_bounds__(256) void k_scan_add(int* __restrict__ offs,
                                                  const int* __restrict__ bbase) {
    int b = blockIdx.x, t = threadIdx.x;
    int i = b * 256 + t;
    if (i < NN) offs[i] += bbase[b];
    if (b == 0 && t == 0) offs[NN] = NE;
}

// 3) atomic-free CSR placement
__global__ void k_fill2(const int* __restrict__ row, const int* __restrict__ col,
                        const float* __restrict__ ew, const int* __restrict__ offs,
                        const int* __restrict__ rank, int* __restrict__ srow,
                        float* __restrict__ sew, int* __restrict__ scol) {
    int e = blockIdx.x * blockDim.x + threadIdx.x;
    if (e < NE) {
        int c = col[e];
        int p = offs[c] + rank[e];
        srow[p] = row[e];
        sew[p]  = ew[e];
        scol[p] = c;
    }
}

// 4) weighted degree from CSR segments (deg = 1 + sum ew), fused rsqrt
__global__ void k_deg_csr(const float* __restrict__ sew, const int* __restrict__ offs,
                          float* __restrict__ dinv, float* __restrict__ selfc) {
    int i = blockIdx.x * blockDim.x + threadIdx.x;
    if (i < NN) {
        float s = 1.0f;
        int a = offs[i], b = offs[i + 1];
        for (int j = a; j < b; ++j) s += sew[j];
        float r = rsqrtf(s);
        dinv[i] = r;
        selfc[i] = r * r;
    }
}

// 5) per-edge symmetric normalization (coalesced; dinv is L2-resident)
__global__ void k_csr_norm(const int* __restrict__ srow, const float* __restrict__ sew,
                           const int* __restrict__ scol, const float* __restrict__ dinv,
                           float* __restrict__ snorm) {
    int p = blockIdx.x * blockDim.x + threadIdx.x;
    if (p < NE) snorm[p] = dinv[srow[p]] * sew[p] * dinv[scol[p]];
}

// ---------------- W packing into MFMA B-fragment layout ----------------
// B-frag for mfma_f32_16x16x32_bf16: lane holds B[k=(lane>>4)*8+j][n=lane&15].
// Packed index: (((nt*4 + s)*64 + lane)*8 + j); k = s*32+(lane>>4)*8+j, n = nt*16+(lane&15).
__global__ __launch_bounds__(256) void k_pack_w(const float* __restrict__ w0,
                                                const float* __restrict__ w1,
                                                const float* __restrict__ w2,
                                                const float* __restrict__ w3,
                                                unsigned short* __restrict__ wpk) {
    int layer = blockIdx.x >> 3;
    int chunk = blockIdx.x & 7;
    const float* W = (layer == 0) ? w0 : (layer == 1) ? w1 : (layer == 2) ? w2 : w3;
    unsigned short* hi = wpk + layer * 32768;
    unsigned short* lo = hi + 16384;
    for (int it = 0; it < 8; ++it) {
        int p = chunk * 2048 + it * 256 + threadIdx.x;
        int j = p & 7, lane = (p >> 3) & 63, s = (p >> 9) & 3, nt = p >> 11;
        int k = s * 32 + ((lane >> 4) << 3) + j;
        int n = nt * 16 + (lane & 15);
        float v = W[k * D + n];
        unsigned short h = f2bf(v);
        hi[p] = h;
        lo[p] = f2bf(v - bf2f(h));
    }
}

// ---------------- MFMA GEMM: H = X @ W (split-bf16, 3 terms) ----------------
template <int AFP32>
__global__ __launch_bounds__(256) void k_gemm_mfma(const float* __restrict__ Xf,
                                                   const unsigned short* __restrict__ Xhi,
                                                   const unsigned short* __restrict__ Xlo,
                                                   const unsigned short* __restrict__ Whi,
                                                   const unsigned short* __restrict__ Wlo,
                                                   float* __restrict__ H) {
    int wid = blockIdx.x * 4 + (threadIdx.x >> 6);
    if (wid >= NN / 16) return;                 // 3125 tiles
    int lane = threadIdx.x & 63;
    int r = wid * 16 + (lane & 15);
    int kg = (lane >> 4) << 3;

    s8v Ahi[4], Alo[4];
    if (AFP32) {
        const float* xr = Xf + (size_t)r * D + kg;
        #pragma unroll
        for (int s = 0; s < 4; ++s) {
            float4 va = *(const float4*)(xr + s * 32);
            float4 vb = *(const float4*)(xr + s * 32 + 4);
            float xv[8] = {va.x, va.y, va.z, va.w, vb.x, vb.y, vb.z, vb.w};
            #pragma unroll
            for (int j = 0; j < 8; ++j) {
                unsigned short h = f2bf(xv[j]);
                Ahi[s][j] = (short)h;
                Alo[s][j] = (short)f2bf(xv[j] - bf2f(h));
            }
        }
    } else {
        const unsigned short* xh = Xhi + (size_t)r * D + kg;
        const unsigned short* xl = Xlo + (size_t)r * D + kg;
        #pragma unroll
        for (int s = 0; s < 4; ++s) {
            Ahi[s] = *(const s8v*)(xh + s * 32);
            Alo[s] = *(const s8v*)(xl + s * 32);
        }
    }

    int cb = lane & 15;
    int rb = wid * 16 + ((lane >> 4) << 2);
    #pragma unroll
    for (int nt = 0; nt < 8; ++nt) {
        f4v acc = {0.f, 0.f, 0.f, 0.f};
        #pragma unroll
        for (int s = 0; s < 4; ++s) {
            int bi = ((nt * 4 + s) * 64 + lane) * 8;
            s8v bh = *(const s8v*)(Whi + bi);
            s8v bl = *(const s8v*)(Wlo + bi);
            acc = __builtin_amdgcn_mfma_f32_16x16x32_bf16(Ahi[s], bh, acc, 0, 0, 0);
            acc = __builtin_amdgcn_mfma_f32_16x16x32_bf16(Alo[s], bh, acc, 0, 0, 0);
            acc = __builtin_amdgcn_mfma_f32_16x16x32_bf16(Ahi[s], bl, acc, 0, 0, 0);
        }
        float* hp = H + (size_t)rb * D + nt * 16 + cb;
        hp[0 * D] = acc[0];
        hp[1 * D] = acc[1];
        hp[2 * D] = acc[2];
        hp[3 * D] = acc[3];
    }
}

// ---------------- aggregation ----------------
__global__ __launch_bounds__(256) void k_agg(const float* __restrict__ Hm,
                                             const int* __restrict__ offs,
                                             const int* __restrict__ srow,
                                             const float* __restrict__ snorm,
                                             const float* __restrict__ selfc,
                                             const float* __restrict__ bias,
                                             unsigned short* __restrict__ outHi,
                                             unsigned short* __restrict__ outLo,
                                             float* __restrict__ outF, int mode) {
    int node = blockIdx.x * 8 + (threadIdx.x >> 5);
    if (node >= NN) return;
    int l4 = (threadIdx.x & 31) * 4;
    float4 acc = *(const float4*)(&Hm[(size_t)node * D + l4]);
    float sc = selfc[node];
    acc.x *= sc; acc.y *= sc; acc.z *= sc; acc.w *= sc;
    int s = offs[node], e = offs[node + 1];
    for (int j = s; j < e; ++j) {
        float w = snorm[j];
        float4 v = *(const float4*)(&Hm[(size_t)srow[j] * D + l4]);
        acc.x += w * v.x; acc.y += w * v.y; acc.z += w * v.z; acc.w += w * v.w;
    }
    float4 b = *(const float4*)(&bias[l4]);
    acc.x += b.x; acc.y += b.y; acc.z += b.z; acc.w += b.w;
    if (mode) {
        acc.x = fmaxf(acc.x, 0.f); acc.y = fmaxf(acc.y, 0.f);
        acc.z = fmaxf(acc.z, 0.f); acc.w = fmaxf(acc.w, 0.f);
        float a[4] = {acc.x, acc.y, acc.z, acc.w};
        s4v hv, lv;
        #pragma unroll
        for (int q = 0; q < 4; ++q) {
            unsigned short h = f2bf(a[q]);
            hv[q] = (short)h;
            lv[q] = (short)f2bf(a[q] - bf2f(h));
        }
        *(s4v*)(outHi + (size_t)node * D + l4) = hv;
        *(s4v*)(outLo + (size_t)node * D + l4) = lv;
    } else {
        *(float4*)(&outF[(size_t)node * D + l4]) = acc;
    }
}

// ---------------- pooling + FC ----------------

#define PCH 128
__global__ __launch_bounds__(128) void k_pool(const float* __restrict__ Hm,
                                              const int* __restrict__ batch,
                                              float* __restrict__ psum,
                                              float* __restrict__ pcnt) {
    int t = threadIdx.x;
    int s = blockIdx.x * PCH;
    int e = min(s + PCH, NN);
    if (s >= NN) return;
    float acc = 0.f;
    int cur = batch[s];
    int cnt = 0;
    for (int n = s; n < e; ++n) {
        int g = batch[n];
        if (g != cur) {
            atomicAdd(&psum[cur * D + t], acc);
            if (t == 0) atomicAdd(&pcnt[cur], (float)cnt);
            acc = 0.f; cnt = 0; cur = g;
        }
        acc += Hm[(size_t)n * D + t];
        cnt++;
    }
    atomicAdd(&psum[cur * D + t], acc);
    if (t == 0) atomicAdd(&pcnt[cur], (float)cnt);
}

__global__ __launch_bounds__(64) void k_fc(const float* __restrict__ psum,
                                           const float* __restrict__ pcnt,
                                           const float* __restrict__ Wfc,
                                           const float* __restrict__ bfc,
                                           float* __restrict__ outp) {
    __shared__ float prow[D];
    int g = blockIdx.x, t = threadIdx.x;
    float inv = 1.0f / fmaxf(pcnt[g], 1.0f);
    prow[t]      = psum[g * D + t] * inv;
    prow[t + 64] = psum[g * D + t + 64] * inv;
    __syncthreads();
    float acc = bfc[t];
    for (int k = 0; k < D; ++k) acc += prow[k] * Wfc[k * OD + t];
    outp[g * OD + t] = acc;
}

// ---------------- launch ----------------

extern "C" void kernel_launch(void* const* d_in, const int* in_sizes, int n_in,
                              void* d_out, int out_size, void* d_ws, size_t ws_size,
                              hipStream_t stream) {
    const float* x    = (const float*)d_in[0];
    const int*   ei   = (const int*)d_in[1];
    const int*   row  = ei;
    const int*   col  = ei + NE;
    const float* ew   = (const float*)d_in[2];
    const int*   batch= (const int*)d_in[3];
    const float* W1 = (const float*)d_in[4];  const float* b1 = (const float*)d_in[5];
    const float* W2 = (const float*)d_in[6];  const float* b2 = (const float*)d_in[7];
    const float* W3 = (const float*)d_in[8];  const float* b3 = (const float*)d_in[9];
    const float* W4 = (const float*)d_in[10]; const float* b4 = (const float*)d_in[11];
    const float* Wfc= (const float*)d_in[12]; const float* bfc= (const float*)d_in[13];

    float* ws = (float*)d_ws;
    float* dinv   = ws + 0;                 // 50048
    float* selfc  = ws + 50048;             // 50048
    int*   counts = (int*)(ws + 100096);    // 50176
    int*   offs   = (int*)(ws + 150272);    // 50176
    int*   rank   = (int*)(ws + 200448);    // 500000 (dead after fill2)
    float* snorm  = ws + 200448;            // aliases rank (written after rank dead)
    int*   srow   = (int*)(ws + 700448);    // 500000
    float* sew    = ws + 1200448;           // 500000
    int*   scol   = (int*)(ws + 1700448);   // 500000
    float* h      = ws + 2200448;           // 6.4M
    float* pair   = ws + 8600448;           // 6.4M (hi|lo bf16, or final fp32)
    unsigned short* pairHi = (unsigned short*)pair;
    unsigned short* pairLo = pairHi + (size_t)NN * D;
    float* psum   = ws + 15000448;          // 65536
    float* pcnt   = ws + 15065984;          // 512
    unsigned short* wpk = (unsigned short*)(ws + 15066496);  // 131072 ushort
    int*   bsum   = (int*)(ws + 15132032);  // 256
    int*   bbase  = (int*)(ws + 15132288);  // 256

    const int TB = 256;
    int nblk = (NN + TB - 1) / TB;   // 196
    int eblk = (NE + TB - 1) / TB;   // 1954

    // CSR build
    hipMemsetAsync(counts, 0, NN * sizeof(int), stream);
    hipMemsetAsync(psum, 0, NG * D * sizeof(float), stream);
    hipMemsetAsync(pcnt, 0, NG * sizeof(float), stream);
    k_pack_w<<<32, 256, 0, stream>>>(W1, W2, W3, W4, wpk);
    k_count_rank<<<eblk, TB, 0, stream>>>(col, counts, rank);
    k_scan_blk<<<nblk, 256, 0, stream>>>(counts, offs, bsum);
    k_scan_top<<<1, 256, 0, stream>>>(bsum, bbase, nblk);
    k_scan_add<<<nblk, 256, 0, stream>>>(offs, bbase);
    k_fill2<<<eblk, TB, 0, stream>>>(row, col, ew, offs, rank, srow, sew, scol);
    k_deg_csr<<<nblk, TB, 0, stream>>>(sew, offs, dinv, selfc);
    k_csr_norm<<<eblk, TB, 0, stream>>>(srow, sew, scol, dinv, snorm);

    const int GB = (NN / 16 + 3) / 4;    // 782 gemm blocks
    const int AB = (NN + 7) / 8;         // 6250 agg blocks

    unsigned short* wh1 = wpk;               unsigned short* wl1 = wpk + 16384;
    unsigned short* wh2 = wpk + 32768;       unsigned short* wl2 = wpk + 49152;
    unsigned short* wh3 = wpk + 65536;       unsigned short* wl3 = wpk + 81920;
    unsigned short* wh4 = wpk + 98304;       unsigned short* wl4 = wpk + 114688;

    // 4 GCN layers
    k_gemm_mfma<1><<<GB, 256, 0, stream>>>(x, nullptr, nullptr, wh1, wl1, h);
    k_agg<<<AB, 256, 0, stream>>>(h, offs, srow, snorm, selfc, b1, pairHi, pairLo, nullptr, 1);
    k_gemm_mfma<0><<<GB, 256, 0, stream>>>(nullptr, pairHi, pairLo, wh2, wl2, h);
    k_agg<<<AB, 256, 0, stream>>>(h, offs, srow, snorm, selfc, b2, pairHi, pairLo, nullptr, 1);
    k_gemm_mfma<0><<<GB, 256, 0, stream>>>(nullptr, pairHi, pairLo, wh3, wl3, h);
    k_agg<<<AB, 256, 0, stream>>>(h, offs, srow, snorm, selfc, b3, pairHi, pairLo, nullptr, 1);
    k_gemm_mfma<0><<<GB, 256, 0, stream>>>(nullptr, pairHi, pairLo, wh4, wl4, h);
    k_agg<<<AB, 256, 0, stream>>>(h, offs, srow, snorm, selfc, b4, nullptr, nullptr, pair, 0);

    // pool + fc
    k_pool<<<(NN + PCH - 1) / PCH, 128, 0, stream>>>(pair, batch, psum, pcnt);
    k_fc<<<NG, 64, 0, stream>>>(psum, pcnt, Wfc, bfc, (float*)d_out);
}

// Round 6
// 304.040 us; speedup vs baseline: 2.4647x; 1.1979x over previous
//
#include <hip/hip_runtime.h>
#include <hip/hip_fp16.h>

#define NN 50000
#define NE 500000
#define D  128
#define OD 64
#define NG 512

typedef __attribute__((ext_vector_type(8))) short s8v;    // 8 bf16 (4 VGPR)
typedef __attribute__((ext_vector_type(4))) short s4v;    // 4 bf16 (8B)
typedef __attribute__((ext_vector_type(4))) float f4v;    // MFMA acc

__device__ inline unsigned short f2bf(float f) {
    unsigned u = __float_as_uint(f);
    unsigned r = (u + 0x7fffu + ((u >> 16) & 1u)) >> 16;   // RNE
    return (unsigned short)r;
}
__device__ inline float bf2f(unsigned short h) {
    return __uint_as_float(((unsigned)h) << 16);
}

struct H4 { __half2 a, b; };   // 4 fp16 = 8B

// ---------------- CSR build (once per call) ----------------
__global__ void k_count_rank(const int* __restrict__ col,
                             int* __restrict__ counts, int* __restrict__ rank) {
    int e = blockIdx.x * blockDim.x + threadIdx.x;
    if (e < NE) rank[e] = atomicAdd(&counts[col[e]], 1);
}

__global__ __launch_bounds__(256) void k_scan_blk(const int* __restrict__ counts,
                                                  int* __restrict__ offs,
                                                  int* __restrict__ bsum) {
    __shared__ int tmp[256];
    int b = blockIdx.x, t = threadIdx.x;
    int i = b * 256 + t;
    int v = (i < NN) ? counts[i] : 0;
    tmp[t] = v;
    __syncthreads();
    for (int st = 1; st < 256; st <<= 1) {
        int u = (t >= st) ? tmp[t - st] : 0;
        __syncthreads();
        tmp[t] += u;
        __syncthreads();
    }
    if (i < NN) offs[i] = tmp[t] - v;
    if (t == 255) bsum[b] = tmp[255];
}

__global__ __launch_bounds__(256) void k_scan_top(const int* __restrict__ bsum,
                                                  int* __restrict__ bbase, int nb) {
    __shared__ int tmp[256];
    int t = threadIdx.x;
    int v = (t < nb) ? bsum[t] : 0;
    tmp[t] = v;
    __syncthreads();
    for (int st = 1; st < 256; st <<= 1) {
        int u = (t >= st) ? tmp[t - st] : 0;
        __syncthreads();
        tmp[t] += u;
        __syncthreads();
    }
    if (t < nb) bbase[t] = tmp[t] - v;
}

__global__ __launch_bounds__(256) void k_scan_add(int* __restrict__ offs,
                                                  const int* __restrict__ bbase) {
    int b = blockIdx.x, t = threadIdx.x;
    int i = b * 256 + t;
    if (i < NN) offs[i] += bbase[b];
    if (b == 0 && t == 0) offs[NN] = NE;
}

__global__ void k_fill2(const int* __restrict__ row, const int* __restrict__ col,
                        const float* __restrict__ ew, const int* __restrict__ offs,
                        const int* __restrict__ rank, int* __restrict__ srow,
                        float* __restrict__ sew, int* __restrict__ scol) {
    int e = blockIdx.x * blockDim.x + threadIdx.x;
    if (e < NE) {
        int c = col[e];
        int p = offs[c] + rank[e];
        srow[p] = row[e];
        sew[p]  = ew[e];
        scol[p] = c;
    }
}

__global__ void k_deg_csr(const float* __restrict__ sew, const int* __restrict__ offs,
                          float* __restrict__ dinv, float* __restrict__ selfc) {
    int i = blockIdx.x * blockDim.x + threadIdx.x;
    if (i < NN) {
        float s = 1.0f;
        int a = offs[i], b = offs[i + 1];
        for (int j = a; j < b; ++j) s += sew[j];
        float r = rsqrtf(s);
        dinv[i] = r;
        selfc[i] = r * r;
    }
}

__global__ void k_csr_norm(const int* __restrict__ srow, const float* __restrict__ sew,
                           const int* __restrict__ scol, const float* __restrict__ dinv,
                           float* __restrict__ snorm) {
    int p = blockIdx.x * blockDim.x + threadIdx.x;
    if (p < NE) snorm[p] = dinv[srow[p]] * sew[p] * dinv[scol[p]];
}

// ---------------- W packing into MFMA B-fragment layout ----------------
__global__ __launch_bounds__(256) void k_pack_w(const float* __restrict__ w0,
                                                const float* __restrict__ w1,
                                                const float* __restrict__ w2,
                                                const float* __restrict__ w3,
                                                unsigned short* __restrict__ wpk) {
    int layer = blockIdx.x >> 3;
    int chunk = blockIdx.x & 7;
    const float* W = (layer == 0) ? w0 : (layer == 1) ? w1 : (layer == 2) ? w2 : w3;
    unsigned short* hi = wpk + layer * 32768;
    unsigned short* lo = hi + 16384;
    for (int it = 0; it < 8; ++it) {
        int p = chunk * 2048 + it * 256 + threadIdx.x;
        int j = p & 7, lane = (p >> 3) & 63, s = (p >> 9) & 3, nt = p >> 11;
        int k = s * 32 + ((lane >> 4) << 3) + j;
        int n = nt * 16 + (lane & 15);
        float v = W[k * D + n];
        unsigned short h = f2bf(v);
        hi[p] = h;
        lo[p] = f2bf(v - bf2f(h));
    }
}

// ---------------- MFMA GEMM: H(fp16) = X @ W (split-bf16, 3 terms) ----------------
template <int AFP32>
__global__ __launch_bounds__(256) void k_gemm_mfma(const float* __restrict__ Xf,
                                                   const unsigned short* __restrict__ Xhi,
                                                   const unsigned short* __restrict__ Xlo,
                                                   const unsigned short* __restrict__ Whi,
                                                   const unsigned short* __restrict__ Wlo,
                                                   __half* __restrict__ H) {
    int wid = blockIdx.x * 4 + (threadIdx.x >> 6);
    if (wid >= NN / 16) return;
    int lane = threadIdx.x & 63;
    int r = wid * 16 + (lane & 15);
    int kg = (lane >> 4) << 3;

    s8v Ahi[4], Alo[4];
    if (AFP32) {
        const float* xr = Xf + (size_t)r * D + kg;
        #pragma unroll
        for (int s = 0; s < 4; ++s) {
            float4 va = *(const float4*)(xr + s * 32);
            float4 vb = *(const float4*)(xr + s * 32 + 4);
            float xv[8] = {va.x, va.y, va.z, va.w, vb.x, vb.y, vb.z, vb.w};
            #pragma unroll
            for (int j = 0; j < 8; ++j) {
                unsigned short h = f2bf(xv[j]);
                Ahi[s][j] = (short)h;
                Alo[s][j] = (short)f2bf(xv[j] - bf2f(h));
            }
        }
    } else {
        const unsigned short* xh = Xhi + (size_t)r * D + kg;
        const unsigned short* xl = Xlo + (size_t)r * D + kg;
        #pragma unroll
        for (int s = 0; s < 4; ++s) {
            Ahi[s] = *(const s8v*)(xh + s * 32);
            Alo[s] = *(const s8v*)(xl + s * 32);
        }
    }

    int cb = lane & 15;
    int rb = wid * 16 + ((lane >> 4) << 2);
    #pragma unroll
    for (int nt = 0; nt < 8; ++nt) {
        f4v acc = {0.f, 0.f, 0.f, 0.f};
        #pragma unroll
        for (int s = 0; s < 4; ++s) {
            int bi = ((nt * 4 + s) * 64 + lane) * 8;
            s8v bh = *(const s8v*)(Whi + bi);
            s8v bl = *(const s8v*)(Wlo + bi);
            acc = __builtin_amdgcn_mfma_f32_16x16x32_bf16(Ahi[s], bh, acc, 0, 0, 0);
            acc = __builtin_amdgcn_mfma_f32_16x16x32_bf16(Alo[s], bh, acc, 0, 0, 0);
            acc = __builtin_amdgcn_mfma_f32_16x16x32_bf16(Ahi[s], bl, acc, 0, 0, 0);
        }
        __half* hp = H + (size_t)rb * D + nt * 16 + cb;
        hp[0 * D] = __float2half(acc[0]);
        hp[1 * D] = __float2half(acc[1]);
        hp[2 * D] = __float2half(acc[2]);
        hp[3 * D] = __float2half(acc[3]);
    }
}

// ---------------- aggregation (gathers fp16 h, accumulates fp32) ----------------
__global__ __launch_bounds__(256) void k_agg(const __half* __restrict__ Hm,
                                             const int* __restrict__ offs,
                                             const int* __restrict__ srow,
                                             const float* __restrict__ snorm,
                                             const float* __restrict__ selfc,
                                             const float* __restrict__ bias,
                                             unsigned short* __restrict__ outHi,
                                             unsigned short* __restrict__ outLo,
                                             float* __restrict__ outF, int mode) {
    int node = blockIdx.x * 8 + (threadIdx.x >> 5);
    if (node >= NN) return;
    int l4 = (threadIdx.x & 31) * 4;
    H4 sv = *(const H4*)(Hm + (size_t)node * D + l4);
    float2 s0 = __half22float2(sv.a), s1 = __half22float2(sv.b);
    float sc = selfc[node];
    float ax = sc * s0.x, ay = sc * s0.y, az = sc * s1.x, aw = sc * s1.y;
    int s = offs[node], e = offs[node + 1];
    int j = s;
    for (; j + 1 < e; j += 2) {
        float w0 = snorm[j],     w1 = snorm[j + 1];
        int   r0 = srow[j],      r1 = srow[j + 1];
        H4 v0 = *(const H4*)(Hm + (size_t)r0 * D + l4);
        H4 v1 = *(const H4*)(Hm + (size_t)r1 * D + l4);
        float2 p0 = __half22float2(v0.a), p1 = __half22float2(v0.b);
        float2 q0 = __half22float2(v1.a), q1 = __half22float2(v1.b);
        ax += w0 * p0.x + w1 * q0.x;
        ay += w0 * p0.y + w1 * q0.y;
        az += w0 * p1.x + w1 * q1.x;
        aw += w0 * p1.y + w1 * q1.y;
    }
    if (j < e) {
        float w0 = snorm[j];
        H4 v0 = *(const H4*)(Hm + (size_t)srow[j] * D + l4);
        float2 p0 = __half22float2(v0.a), p1 = __half22float2(v0.b);
        ax += w0 * p0.x; ay += w0 * p0.y; az += w0 * p1.x; aw += w0 * p1.y;
    }
    float4 b = *(const float4*)(&bias[l4]);
    ax += b.x; ay += b.y; az += b.z; aw += b.w;
    if (mode) {
        ax = fmaxf(ax, 0.f); ay = fmaxf(ay, 0.f);
        az = fmaxf(az, 0.f); aw = fmaxf(aw, 0.f);
        float a[4] = {ax, ay, az, aw};
        s4v hv, lv;
        #pragma unroll
        for (int q = 0; q < 4; ++q) {
            unsigned short h = f2bf(a[q]);
            hv[q] = (short)h;
            lv[q] = (short)f2bf(a[q] - bf2f(h));
        }
        *(s4v*)(outHi + (size_t)node * D + l4) = hv;
        *(s4v*)(outLo + (size_t)node * D + l4) = lv;
    } else {
        float4 o = make_float4(ax, ay, az, aw);
        *(float4*)(&outF[(size_t)node * D + l4]) = o;
    }
}

// ---------------- pooling + FC ----------------

#define PCH 128
__global__ __launch_bounds__(128) void k_pool(const float* __restrict__ Hm,
                                              const int* __restrict__ batch,
                                              float* __restrict__ psum,
                                              float* __restrict__ pcnt) {
    int t = threadIdx.x;
    int s = blockIdx.x * PCH;
    int e = min(s + PCH, NN);
    if (s >= NN) return;
    float acc = 0.f;
    int cur = batch[s];
    int cnt = 0;
    for (int n = s; n < e; ++n) {
        int g = batch[n];
        if (g != cur) {
            atomicAdd(&psum[cur * D + t], acc);
            if (t == 0) atomicAdd(&pcnt[cur], (float)cnt);
            acc = 0.f; cnt = 0; cur = g;
        }
        acc += Hm[(size_t)n * D + t];
        cnt++;
    }
    atomicAdd(&psum[cur * D + t], acc);
    if (t == 0) atomicAdd(&pcnt[cur], (float)cnt);
}

__global__ __launch_bounds__(64) void k_fc(const float* __restrict__ psum,
                                           const float* __restrict__ pcnt,
                                           const float* __restrict__ Wfc,
                                           const float* __restrict__ bfc,
                                           float* __restrict__ outp) {
    __shared__ float prow[D];
    int g = blockIdx.x, t = threadIdx.x;
    float inv = 1.0f / fmaxf(pcnt[g], 1.0f);
    prow[t]      = psum[g * D + t] * inv;
    prow[t + 64] = psum[g * D + t + 64] * inv;
    __syncthreads();
    float acc = bfc[t];
    for (int k = 0; k < D; ++k) acc += prow[k] * Wfc[k * OD + t];
    outp[g * OD + t] = acc;
}

// ---------------- launch ----------------

extern "C" void kernel_launch(void* const* d_in, const int* in_sizes, int n_in,
                              void* d_out, int out_size, void* d_ws, size_t ws_size,
                              hipStream_t stream) {
    const float* x    = (const float*)d_in[0];
    const int*   ei   = (const int*)d_in[1];
    const int*   row  = ei;
    const int*   col  = ei + NE;
    const float* ew   = (const float*)d_in[2];
    const int*   batch= (const int*)d_in[3];
    const float* W1 = (const float*)d_in[4];  const float* b1 = (const float*)d_in[5];
    const float* W2 = (const float*)d_in[6];  const float* b2 = (const float*)d_in[7];
    const float* W3 = (const float*)d_in[8];  const float* b3 = (const float*)d_in[9];
    const float* W4 = (const float*)d_in[10]; const float* b4 = (const float*)d_in[11];
    const float* Wfc= (const float*)d_in[12]; const float* bfc= (const float*)d_in[13];

    float* ws = (float*)d_ws;
    float* dinv   = ws + 0;                 // 50048
    float* selfc  = ws + 50048;             // 50048
    int*   counts = (int*)(ws + 100096);    // 50176
    int*   offs   = (int*)(ws + 150272);    // 50176
    int*   rank   = (int*)(ws + 200448);    // 500000 (dead after fill2)
    float* snorm  = ws + 200448;            // aliases rank (written after rank dead)
    int*   srow   = (int*)(ws + 700448);    // 500000
    float* sew    = ws + 1200448;           // 500000
    int*   scol   = (int*)(ws + 1700448);   // 500000
    __half* h     = (__half*)(ws + 2200448);// 6.4M fp16 (3.2M floats used)
    float* pair   = ws + 8600448;           // 6.4M (hi|lo bf16, or final fp32)
    unsigned short* pairHi = (unsigned short*)pair;
    unsigned short* pairLo = pairHi + (size_t)NN * D;
    float* psum   = ws + 15000448;          // 65536
    float* pcnt   = ws + 15065984;          // 512
    unsigned short* wpk = (unsigned short*)(ws + 15066496);  // 131072 ushort
    int*   bsum   = (int*)(ws + 15132032);  // 256
    int*   bbase  = (int*)(ws + 15132288);  // 256

    const int TB = 256;
    int nblk = (NN + TB - 1) / TB;   // 196
    int eblk = (NE + TB - 1) / TB;   // 1954

    // CSR build
    hipMemsetAsync(counts, 0, NN * sizeof(int), stream);
    hipMemsetAsync(psum, 0, NG * D * sizeof(float), stream);
    hipMemsetAsync(pcnt, 0, NG * sizeof(float), stream);
    k_pack_w<<<32, 256, 0, stream>>>(W1, W2, W3, W4, wpk);
    k_count_rank<<<eblk, TB, 0, stream>>>(col, counts, rank);
    k_scan_blk<<<nblk, 256, 0, stream>>>(counts, offs, bsum);
    k_scan_top<<<1, 256, 0, stream>>>(bsum, bbase, nblk);
    k_scan_add<<<nblk, 256, 0, stream>>>(offs, bbase);
    k_fill2<<<eblk, TB, 0, stream>>>(row, col, ew, offs, rank, srow, sew, scol);
    k_deg_csr<<<nblk, TB, 0, stream>>>(sew, offs, dinv, selfc);
    k_csr_norm<<<eblk, TB, 0, stream>>>(srow, sew, scol, dinv, snorm);

    const int GB = (NN / 16 + 3) / 4;    // 782 gemm blocks
    const int AB = (NN + 7) / 8;         // 6250 agg blocks

    unsigned short* wh1 = wpk;               unsigned short* wl1 = wpk + 16384;
    unsigned short* wh2 = wpk + 32768;       unsigned short* wl2 = wpk + 49152;
    unsigned short* wh3 = wpk + 65536;       unsigned short* wl3 = wpk + 81920;
    unsigned short* wh4 = wpk + 98304;       unsigned short* wl4 = wpk + 114688;

    // 4 GCN layers
    k_gemm_mfma<1><<<GB, 256, 0, stream>>>(x, nullptr, nullptr, wh1, wl1, h);
    k_agg<<<AB, 256, 0, stream>>>(h, offs, srow, snorm, selfc, b1, pairHi, pairLo, nullptr, 1);
    k_gemm_mfma<0><<<GB, 256, 0, stream>>>(nullptr, pairHi, pairLo, wh2, wl2, h);
    k_agg<<<AB, 256, 0, stream>>>(h, offs, srow, snorm, selfc, b2, pairHi, pairLo, nullptr, 1);
    k_gemm_mfma<0><<<GB, 256, 0, stream>>>(nullptr, pairHi, pairLo, wh3, wl3, h);
    k_agg<<<AB, 256, 0, stream>>>(h, offs, srow, snorm, selfc, b3, pairHi, pairLo, nullptr, 1);
    k_gemm_mfma<0><<<GB, 256, 0, stream>>>(nullptr, pairHi, pairLo, wh4, wl4, h);
    k_agg<<<AB, 256, 0, stream>>>(h, offs, srow, snorm, selfc, b4, nullptr, nullptr, pair, 0);

    // pool + fc
    k_pool<<<(NN + PCH - 1) / PCH, 128, 0, stream>>>(pair, batch, psum, pcnt);
    k_fc<<<NG, 64, 0, stream>>>(psum, pcnt, Wfc, bfc, (float*)d_out);
}

// Round 7
// 267.047 us; speedup vs baseline: 2.8062x; 1.1385x over previous
//
#include <hip/hip_runtime.h>
#include <hip/hip_fp16.h>

#define NN 50000
#define NE 500000
#define D  128
#define OD 64
#define NG 512

typedef __attribute__((ext_vector_type(8))) short s8v;    // 8 bf16 (4 VGPR)
typedef __attribute__((ext_vector_type(4))) short s4v;    // 4 bf16 (8B)
typedef __attribute__((ext_vector_type(4))) float f4v;    // MFMA acc

__device__ inline unsigned short f2bf(float f) {
    unsigned u = __float_as_uint(f);
    unsigned r = (u + 0x7fffu + ((u >> 16) & 1u)) >> 16;   // RNE
    return (unsigned short)r;
}
__device__ inline float bf2f(unsigned short h) {
    return __uint_as_float(((unsigned)h) << 16);
}

struct H4 { __half2 a, b; };   // 4 fp16 = 8B

// ---------------- CSR build (once per call) ----------------
__global__ void k_count_rank(const int* __restrict__ col,
                             int* __restrict__ counts, int* __restrict__ rank) {
    int e = blockIdx.x * blockDim.x + threadIdx.x;
    if (e < NE) rank[e] = atomicAdd(&counts[col[e]], 1);
}

__global__ __launch_bounds__(256) void k_scan_blk(const int* __restrict__ counts,
                                                  int* __restrict__ offs,
                                                  int* __restrict__ bsum) {
    __shared__ int tmp[256];
    int b = blockIdx.x, t = threadIdx.x;
    int i = b * 256 + t;
    int v = (i < NN) ? counts[i] : 0;
    tmp[t] = v;
    __syncthreads();
    for (int st = 1; st < 256; st <<= 1) {
        int u = (t >= st) ? tmp[t - st] : 0;
        __syncthreads();
        tmp[t] += u;
        __syncthreads();
    }
    if (i < NN) offs[i] = tmp[t] - v;
    if (t == 255) bsum[b] = tmp[255];
}

__global__ __launch_bounds__(256) void k_scan_top(const int* __restrict__ bsum,
                                                  int* __restrict__ bbase, int nb) {
    __shared__ int tmp[256];
    int t = threadIdx.x;
    int v = (t < nb) ? bsum[t] : 0;
    tmp[t] = v;
    __syncthreads();
    for (int st = 1; st < 256; st <<= 1) {
        int u = (t >= st) ? tmp[t - st] : 0;
        __syncthreads();
        tmp[t] += u;
        __syncthreads();
    }
    if (t < nb) bbase[t] = tmp[t] - v;
}

__global__ __launch_bounds__(256) void k_scan_add(int* __restrict__ offs,
                                                  const int* __restrict__ bbase) {
    int b = blockIdx.x, t = threadIdx.x;
    int i = b * 256 + t;
    if (i < NN) offs[i] += bbase[b];
    if (b == 0 && t == 0) offs[NN] = NE;
}

__global__ void k_fill2(const int* __restrict__ row, const int* __restrict__ col,
                        const float* __restrict__ ew, const int* __restrict__ offs,
                        const int* __restrict__ rank, int* __restrict__ srow,
                        float* __restrict__ sew, int* __restrict__ scol) {
    int e = blockIdx.x * blockDim.x + threadIdx.x;
    if (e < NE) {
        int c = col[e];
        int p = offs[c] + rank[e];
        srow[p] = row[e];
        sew[p]  = ew[e];
        scol[p] = c;
    }
}

__global__ void k_deg_csr(const float* __restrict__ sew, const int* __restrict__ offs,
                          float* __restrict__ dinv, float* __restrict__ selfc) {
    int i = blockIdx.x * blockDim.x + threadIdx.x;
    if (i < NN) {
        float s = 1.0f;
        int a = offs[i], b = offs[i + 1];
        for (int j = a; j < b; ++j) s += sew[j];
        float r = rsqrtf(s);
        dinv[i] = r;
        selfc[i] = r * r;
    }
}

__global__ void k_csr_norm(const int* __restrict__ srow, const float* __restrict__ sew,
                           const int* __restrict__ scol, const float* __restrict__ dinv,
                           float* __restrict__ snorm) {
    int p = blockIdx.x * blockDim.x + threadIdx.x;
    if (p < NE) snorm[p] = dinv[srow[p]] * sew[p] * dinv[scol[p]];
}

// ---------------- W packing into MFMA B-fragment layout ----------------
__global__ __launch_bounds__(256) void k_pack_w(const float* __restrict__ w0,
                                                const float* __restrict__ w1,
                                                const float* __restrict__ w2,
                                                const float* __restrict__ w3,
                                                unsigned short* __restrict__ wpk) {
    int layer = blockIdx.x >> 3;
    int chunk = blockIdx.x & 7;
    const float* W = (layer == 0) ? w0 : (layer == 1) ? w1 : (layer == 2) ? w2 : w3;
    unsigned short* hi = wpk + layer * 32768;
    unsigned short* lo = hi + 16384;
    for (int it = 0; it < 8; ++it) {
        int p = chunk * 2048 + it * 256 + threadIdx.x;
        int j = p & 7, lane = (p >> 3) & 63, s = (p >> 9) & 3, nt = p >> 11;
        int k = s * 32 + ((lane >> 4) << 3) + j;
        int n = nt * 16 + (lane & 15);
        float v = W[k * D + n];
        unsigned short h = f2bf(v);
        hi[p] = h;
        lo[p] = f2bf(v - bf2f(h));
    }
}

// ---------------- MFMA GEMM: H(fp16) = X @ W (split-bf16, 3 terms) ----------------
// 512-thread block = 8 waves, each owning one 16-row tile; W-pair (64 KB)
// staged in LDS once per block, B-frags via conflict-free ds_read_b128.
template <int AFP32>
__global__ __launch_bounds__(512) void k_gemm_mfma(const float* __restrict__ Xf,
                                                   const unsigned short* __restrict__ Xhi,
                                                   const unsigned short* __restrict__ Xlo,
                                                   const unsigned short* __restrict__ Wl,
                                                   __half* __restrict__ H) {
    __shared__ unsigned short Ws[32768];       // hi[16384] | lo[16384] = 64 KB
    int t = threadIdx.x;
    {
        const float4* src = (const float4*)Wl;
        float4* dst = (float4*)Ws;
        #pragma unroll
        for (int i = 0; i < 8; ++i) dst[t + i * 512] = src[t + i * 512];
    }
    __syncthreads();

    int wid = blockIdx.x * 8 + (t >> 6);
    if (wid >= NN / 16) return;                 // 3125 tiles
    int lane = t & 63;
    int r = wid * 16 + (lane & 15);
    int kg = (lane >> 4) << 3;

    s8v Ahi[4], Alo[4];
    if (AFP32) {
        const float* xr = Xf + (size_t)r * D + kg;
        #pragma unroll
        for (int s = 0; s < 4; ++s) {
            float4 va = *(const float4*)(xr + s * 32);
            float4 vb = *(const float4*)(xr + s * 32 + 4);
            float xv[8] = {va.x, va.y, va.z, va.w, vb.x, vb.y, vb.z, vb.w};
            #pragma unroll
            for (int j = 0; j < 8; ++j) {
                unsigned short h = f2bf(xv[j]);
                Ahi[s][j] = (short)h;
                Alo[s][j] = (short)f2bf(xv[j] - bf2f(h));
            }
        }
    } else {
        const unsigned short* xh = Xhi + (size_t)r * D + kg;
        const unsigned short* xl = Xlo + (size_t)r * D + kg;
        #pragma unroll
        for (int s = 0; s < 4; ++s) {
            Ahi[s] = *(const s8v*)(xh + s * 32);
            Alo[s] = *(const s8v*)(xl + s * 32);
        }
    }

    int cb = lane & 15;
    int rb = wid * 16 + ((lane >> 4) << 2);
    #pragma unroll
    for (int nt = 0; nt < 8; ++nt) {
        f4v acc = {0.f, 0.f, 0.f, 0.f};
        #pragma unroll
        for (int s = 0; s < 4; ++s) {
            int off = ((nt * 4 + s) * 64 + lane) * 8;
            s8v bh = *(const s8v*)(Ws + off);
            s8v bl = *(const s8v*)(Ws + 16384 + off);
            acc = __builtin_amdgcn_mfma_f32_16x16x32_bf16(Ahi[s], bh, acc, 0, 0, 0);
            acc = __builtin_amdgcn_mfma_f32_16x16x32_bf16(Alo[s], bh, acc, 0, 0, 0);
            acc = __builtin_amdgcn_mfma_f32_16x16x32_bf16(Ahi[s], bl, acc, 0, 0, 0);
        }
        __half* hp = H + (size_t)rb * D + nt * 16 + cb;
        hp[0 * D] = __float2half(acc[0]);
        hp[1 * D] = __float2half(acc[1]);
        hp[2 * D] = __float2half(acc[2]);
        hp[3 * D] = __float2half(acc[3]);
    }
}

// ---------------- aggregation (gathers fp16 h, accumulates fp32) ----------------
// mode 1: relu + split-bf16 pair out (next GEMM input). mode 0: fp16 out (pool input).
__global__ __launch_bounds__(256) void k_agg(const __half* __restrict__ Hm,
                                             const int* __restrict__ offs,
                                             const int* __restrict__ srow,
                                             const float* __restrict__ snorm,
                                             const float* __restrict__ selfc,
                                             const float* __restrict__ bias,
                                             unsigned short* __restrict__ outHi,
                                             unsigned short* __restrict__ outLo,
                                             __half* __restrict__ outF, int mode) {
    int node = blockIdx.x * 8 + (threadIdx.x >> 5);
    if (node >= NN) return;
    int l4 = (threadIdx.x & 31) * 4;
    H4 sv = *(const H4*)(Hm + (size_t)node * D + l4);
    float2 s0 = __half22float2(sv.a), s1 = __half22float2(sv.b);
    float sc = selfc[node];
    float ax = sc * s0.x, ay = sc * s0.y, az = sc * s1.x, aw = sc * s1.y;
    int s = offs[node], e = offs[node + 1];
    int j = s;
    for (; j + 3 < e; j += 4) {
        float w0 = snorm[j],   w1 = snorm[j+1], w2 = snorm[j+2], w3 = snorm[j+3];
        int   r0 = srow[j],    r1 = srow[j+1],  r2 = srow[j+2],  r3 = srow[j+3];
        H4 v0 = *(const H4*)(Hm + (size_t)r0 * D + l4);
        H4 v1 = *(const H4*)(Hm + (size_t)r1 * D + l4);
        H4 v2 = *(const H4*)(Hm + (size_t)r2 * D + l4);
        H4 v3 = *(const H4*)(Hm + (size_t)r3 * D + l4);
        float2 p0 = __half22float2(v0.a), p1 = __half22float2(v0.b);
        float2 q0 = __half22float2(v1.a), q1 = __half22float2(v1.b);
        float2 u0 = __half22float2(v2.a), u1 = __half22float2(v2.b);
        float2 t0 = __half22float2(v3.a), t1 = __half22float2(v3.b);
        ax += w0 * p0.x + w1 * q0.x + w2 * u0.x + w3 * t0.x;
        ay += w0 * p0.y + w1 * q0.y + w2 * u0.y + w3 * t0.y;
        az += w0 * p1.x + w1 * q1.x + w2 * u1.x + w3 * t1.x;
        aw += w0 * p1.y + w1 * q1.y + w2 * u1.y + w3 * t1.y;
    }
    for (; j < e; ++j) {
        float w0 = snorm[j];
        H4 v0 = *(const H4*)(Hm + (size_t)srow[j] * D + l4);
        float2 p0 = __half22float2(v0.a), p1 = __half22float2(v0.b);
        ax += w0 * p0.x; ay += w0 * p0.y; az += w0 * p1.x; aw += w0 * p1.y;
    }
    float4 b = *(const float4*)(&bias[l4]);
    ax += b.x; ay += b.y; az += b.z; aw += b.w;
    if (mode) {
        ax = fmaxf(ax, 0.f); ay = fmaxf(ay, 0.f);
        az = fmaxf(az, 0.f); aw = fmaxf(aw, 0.f);
        float a[4] = {ax, ay, az, aw};
        s4v hv, lv;
        #pragma unroll
        for (int q = 0; q < 4; ++q) {
            unsigned short h = f2bf(a[q]);
            hv[q] = (short)h;
            lv[q] = (short)f2bf(a[q] - bf2f(h));
        }
        *(s4v*)(outHi + (size_t)node * D + l4) = hv;
        *(s4v*)(outLo + (size_t)node * D + l4) = lv;
    } else {
        H4 o;
        o.a = __floats2half2_rn(ax, ay);
        o.b = __floats2half2_rn(az, aw);
        *(H4*)(outF + (size_t)node * D + l4) = o;
    }
}

// ---------------- pooling + FC ----------------

#define PCH 128
__global__ __launch_bounds__(128) void k_pool(const __half* __restrict__ Hm,
                                              const int* __restrict__ batch,
                                              float* __restrict__ psum,
                                              float* __restrict__ pcnt) {
    int t = threadIdx.x;
    int s = blockIdx.x * PCH;
    int e = min(s + PCH, NN);
    if (s >= NN) return;
    float acc = 0.f;
    int cur = batch[s];
    int cnt = 0;
    for (int n = s; n < e; ++n) {
        int g = batch[n];
        if (g != cur) {
            atomicAdd(&psum[cur * D + t], acc);
            if (t == 0) atomicAdd(&pcnt[cur], (float)cnt);
            acc = 0.f; cnt = 0; cur = g;
        }
        acc += __half2float(Hm[(size_t)n * D + t]);
        cnt++;
    }
    atomicAdd(&psum[cur * D + t], acc);
    if (t == 0) atomicAdd(&pcnt[cur], (float)cnt);
}

__global__ __launch_bounds__(64) void k_fc(const float* __restrict__ psum,
                                           const float* __restrict__ pcnt,
                                           const float* __restrict__ Wfc,
                                           const float* __restrict__ bfc,
                                           float* __restrict__ outp) {
    __shared__ float prow[D];
    int g = blockIdx.x, t = threadIdx.x;
    float inv = 1.0f / fmaxf(pcnt[g], 1.0f);
    prow[t]      = psum[g * D + t] * inv;
    prow[t + 64] = psum[g * D + t + 64] * inv;
    __syncthreads();
    float acc = bfc[t];
    for (int k = 0; k < D; ++k) acc += prow[k] * Wfc[k * OD + t];
    outp[g * OD + t] = acc;
}

// ---------------- launch ----------------

extern "C" void kernel_launch(void* const* d_in, const int* in_sizes, int n_in,
                              void* d_out, int out_size, void* d_ws, size_t ws_size,
                              hipStream_t stream) {
    const float* x    = (const float*)d_in[0];
    const int*   ei   = (const int*)d_in[1];
    const int*   row  = ei;
    const int*   col  = ei + NE;
    const float* ew   = (const float*)d_in[2];
    const int*   batch= (const int*)d_in[3];
    const float* W1 = (const float*)d_in[4];  const float* b1 = (const float*)d_in[5];
    const float* W2 = (const float*)d_in[6];  const float* b2 = (const float*)d_in[7];
    const float* W3 = (const float*)d_in[8];  const float* b3 = (const float*)d_in[9];
    const float* W4 = (const float*)d_in[10]; const float* b4 = (const float*)d_in[11];
    const float* Wfc= (const float*)d_in[12]; const float* bfc= (const float*)d_in[13];

    float* ws = (float*)d_ws;
    float* dinv   = ws + 0;                 // 50048
    float* selfc  = ws + 50048;             // 50048
    int*   counts = (int*)(ws + 100096);    // 50176
    int*   offs   = (int*)(ws + 150272);    // 50176
    int*   rank   = (int*)(ws + 200448);    // 500000 (dead after fill2)
    float* snorm  = ws + 200448;            // aliases rank (written after rank dead)
    int*   srow   = (int*)(ws + 700448);    // 500000
    float* sew    = ws + 1200448;           // 500000
    int*   scol   = (int*)(ws + 1700448);   // 500000
    __half* h     = (__half*)(ws + 2200448);// 6.4M fp16
    float* pair   = ws + 8600448;           // 6.4M (hi|lo bf16; final fp16)
    unsigned short* pairHi = (unsigned short*)pair;
    unsigned short* pairLo = pairHi + (size_t)NN * D;
    __half* hfin  = (__half*)pair;
    float* psum   = ws + 15000448;          // 65536
    float* pcnt   = ws + 15065984;          // 512
    unsigned short* wpk = (unsigned short*)(ws + 15066496);  // 131072 ushort
    int*   bsum   = (int*)(ws + 15132032);  // 256
    int*   bbase  = (int*)(ws + 15132288);  // 256

    const int TB = 256;
    int nblk = (NN + TB - 1) / TB;   // 196
    int eblk = (NE + TB - 1) / TB;   // 1954

    // CSR build
    hipMemsetAsync(counts, 0, NN * sizeof(int), stream);
    hipMemsetAsync(psum, 0, NG * D * sizeof(float), stream);
    hipMemsetAsync(pcnt, 0, NG * sizeof(float), stream);
    k_pack_w<<<32, 256, 0, stream>>>(W1, W2, W3, W4, wpk);
    k_count_rank<<<eblk, TB, 0, stream>>>(col, counts, rank);
    k_scan_blk<<<nblk, 256, 0, stream>>>(counts, offs, bsum);
    k_scan_top<<<1, 256, 0, stream>>>(bsum, bbase, nblk);
    k_scan_add<<<nblk, 256, 0, stream>>>(offs, bbase);
    k_fill2<<<eblk, TB, 0, stream>>>(row, col, ew, offs, rank, srow, sew, scol);
    k_deg_csr<<<nblk, TB, 0, stream>>>(sew, offs, dinv, selfc);
    k_csr_norm<<<eblk, TB, 0, stream>>>(srow, sew, scol, dinv, snorm);

    const int GB = (NN / 16 + 7) / 8;    // 391 gemm blocks (8 waves each)
    const int AB = (NN + 7) / 8;         // 6250 agg blocks

    unsigned short* wp1 = wpk;
    unsigned short* wp2 = wpk + 32768;
    unsigned short* wp3 = wpk + 65536;
    unsigned short* wp4 = wpk + 98304;

    // 4 GCN layers
    k_gemm_mfma<1><<<GB, 512, 0, stream>>>(x, nullptr, nullptr, wp1, h);
    k_agg<<<AB, 256, 0, stream>>>(h, offs, srow, snorm, selfc, b1, pairHi, pairLo, nullptr, 1);
    k_gemm_mfma<0><<<GB, 512, 0, stream>>>(nullptr, pairHi, pairLo, wp2, h);
    k_agg<<<AB, 256, 0, stream>>>(h, offs, srow, snorm, selfc, b2, pairHi, pairLo, nullptr, 1);
    k_gemm_mfma<0><<<GB, 512, 0, stream>>>(nullptr, pairHi, pairLo, wp3, h);
    k_agg<<<AB, 256, 0, stream>>>(h, offs, srow, snorm, selfc, b3, pairHi, pairLo, nullptr, 1);
    k_gemm_mfma<0><<<GB, 512, 0, stream>>>(nullptr, pairHi, pairLo, wp4, h);
    k_agg<<<AB, 256, 0, stream>>>(h, offs, srow, snorm, selfc, b4, nullptr, nullptr, hfin, 0);

    // pool + fc
    k_pool<<<(NN + PCH - 1) / PCH, 128, 0, stream>>>(hfin, batch, psum, pcnt);
    k_fc<<<NG, 64, 0, stream>>>(psum, pcnt, Wfc, bfc, (float*)d_out);
}

// Round 8
// 265.829 us; speedup vs baseline: 2.8190x; 1.0046x over previous
//
#include <hip/hip_runtime.h>
#include <hip/hip_fp16.h>

#define NN 50000
#define NE 500000
#define D  128
#define OD 64
#define NG 512

typedef __attribute__((ext_vector_type(8))) short s8v;    // 8 bf16/fp16 (16B)
typedef __attribute__((ext_vector_type(4))) float f4v;    // MFMA acc

__device__ inline unsigned short f2bf(float f) {
    unsigned u = __float_as_uint(f);
    unsigned r = (u + 0x7fffu + ((u >> 16) & 1u)) >> 16;   // RNE
    return (unsigned short)r;
}
__device__ inline float bf2f(unsigned short h) {
    return __uint_as_float(((unsigned)h) << 16);
}

struct H4 { __half2 a, b; };   // 4 fp16 = 8B

// ---------------- CSR build (once per call) ----------------
__global__ void k_count_rank(const int* __restrict__ col,
                             int* __restrict__ counts, int* __restrict__ rank) {
    int e = blockIdx.x * blockDim.x + threadIdx.x;
    if (e < NE) rank[e] = atomicAdd(&counts[col[e]], 1);
}

__global__ __launch_bounds__(256) void k_scan_blk(const int* __restrict__ counts,
                                                  int* __restrict__ offs,
                                                  int* __restrict__ bsum) {
    __shared__ int tmp[256];
    int b = blockIdx.x, t = threadIdx.x;
    int i = b * 256 + t;
    int v = (i < NN) ? counts[i] : 0;
    tmp[t] = v;
    __syncthreads();
    for (int st = 1; st < 256; st <<= 1) {
        int u = (t >= st) ? tmp[t - st] : 0;
        __syncthreads();
        tmp[t] += u;
        __syncthreads();
    }
    if (i < NN) offs[i] = tmp[t] - v;
    if (t == 255) bsum[b] = tmp[255];
}

__global__ __launch_bounds__(256) void k_scan_top(const int* __restrict__ bsum,
                                                  int* __restrict__ bbase, int nb) {
    __shared__ int tmp[256];
    int t = threadIdx.x;
    int v = (t < nb) ? bsum[t] : 0;
    tmp[t] = v;
    __syncthreads();
    for (int st = 1; st < 256; st <<= 1) {
        int u = (t >= st) ? tmp[t - st] : 0;
        __syncthreads();
        tmp[t] += u;
        __syncthreads();
    }
    if (t < nb) bbase[t] = tmp[t] - v;
}

__global__ __launch_bounds__(256) void k_scan_add(int* __restrict__ offs,
                                                  const int* __restrict__ bbase) {
    int b = blockIdx.x, t = threadIdx.x;
    int i = b * 256 + t;
    if (i < NN) offs[i] += bbase[b];
    if (b == 0 && t == 0) offs[NN] = NE;
}

__global__ void k_fill2(const int* __restrict__ row, const int* __restrict__ col,
                        const float* __restrict__ ew, const int* __restrict__ offs,
                        const int* __restrict__ rank, int* __restrict__ srow,
                        float* __restrict__ sew) {
    int e = blockIdx.x * blockDim.x + threadIdx.x;
    if (e < NE) {
        int p = offs[col[e]] + rank[e];
        srow[p] = row[e];
        sew[p]  = ew[e];
    }
}

__global__ void k_deg_csr(const float* __restrict__ sew, const int* __restrict__ offs,
                          float* __restrict__ dinv, float* __restrict__ selfc) {
    int i = blockIdx.x * blockDim.x + threadIdx.x;
    if (i < NN) {
        float s = 1.0f;
        int a = offs[i], b = offs[i + 1];
        for (int j = a; j < b; ++j) s += sew[j];
        float r = rsqrtf(s);
        dinv[i] = r;
        selfc[i] = r * r;
    }
}

// node-parallel: snorm[j] = dinv[c]*sew[j]*dinv[srow[j]]  (no scol needed)
__global__ void k_csr_norm(const int* __restrict__ srow, const float* __restrict__ sew,
                           const int* __restrict__ offs, const float* __restrict__ dinv,
                           float* __restrict__ snorm) {
    int i = blockIdx.x * blockDim.x + threadIdx.x;
    if (i < NN) {
        float di = dinv[i];
        int a = offs[i], b = offs[i + 1];
        for (int j = a; j < b; ++j) snorm[j] = di * sew[j] * dinv[srow[j]];
    }
}

// ---------------- x -> fp16 ----------------
__global__ __launch_bounds__(256) void k_x2h(const float* __restrict__ x,
                                             __half* __restrict__ xh) {
    int i = blockIdx.x * 256 + threadIdx.x;
    if (i < NN * D / 4) {
        float4 v = ((const float4*)x)[i];
        H4 o;
        o.a = __floats2half2_rn(v.x, v.y);
        o.b = __floats2half2_rn(v.z, v.w);
        ((H4*)xh)[i] = o;
    }
}

// ---------------- W packing into MFMA B-fragment layout (layers 1-3) ----------------
// B-frag for mfma_f32_16x16x32_bf16: lane holds B[k=(lane>>4)*8+j][n=lane&15].
// Packed index: (((nt*4 + s)*64 + lane)*8 + j); k = s*32+(lane>>4)*8+j, n = nt*16+(lane&15).
__global__ __launch_bounds__(256) void k_pack_w(const float* __restrict__ w0,
                                                const float* __restrict__ w1,
                                                const float* __restrict__ w2,
                                                unsigned short* __restrict__ wpk) {
    int layer = blockIdx.x >> 3;
    int chunk = blockIdx.x & 7;
    const float* W = (layer == 0) ? w0 : (layer == 1) ? w1 : w2;
    unsigned short* hi = wpk + layer * 32768;
    unsigned short* lo = hi + 16384;
    for (int it = 0; it < 8; ++it) {
        int p = chunk * 2048 + it * 256 + threadIdx.x;
        int j = p & 7, lane = (p >> 3) & 63, s = (p >> 9) & 3, nt = p >> 11;
        int k = s * 32 + ((lane >> 4) << 3) + j;
        int n = nt * 16 + (lane & 15);
        float v = W[k * D + n];
        unsigned short h = f2bf(v);
        hi[p] = h;
        lo[p] = f2bf(v - bf2f(h));
    }
}

// ---------------- Wcomb = W4 @ Wfc ; bcomb = b4 @ Wfc + bfc ----------------
__global__ __launch_bounds__(256) void k_comb_w(const float* __restrict__ W4,
                                                const float* __restrict__ Wfc,
                                                const float* __restrict__ b4,
                                                const float* __restrict__ bfc,
                                                float* __restrict__ Wcomb,
                                                float* __restrict__ bcomb) {
    int id = blockIdx.x * 256 + threadIdx.x;
    if (id < D * OD) {
        int k = id >> 6, n = id & 63;
        float s = 0.f;
        for (int j = 0; j < D; ++j) s += W4[k * D + j] * Wfc[j * OD + n];
        Wcomb[id] = s;
    }
    if (id < OD) {
        float s = bfc[id];
        for (int j = 0; j < D; ++j) s += b4[j] * Wfc[j * OD + id];
        bcomb[id] = s;
    }
}

// ---------------- MFMA GEMM: H(fp16) = relu(A @ W + b) (split-bf16, 3 terms) ----------------
// A fp16 expanded to bf16 hi/lo in-register (exact); W-pair staged in LDS.
__global__ __launch_bounds__(512) void k_gemm_mfma(const __half* __restrict__ A,
                                                   const unsigned short* __restrict__ Wl,
                                                   const float* __restrict__ bias,
                                                   __half* __restrict__ H) {
    __shared__ unsigned short Ws[32768];       // hi[16384] | lo[16384] = 64 KB
    int t = threadIdx.x;
    {
        const float4* src = (const float4*)Wl;
        float4* dst = (float4*)Ws;
        #pragma unroll
        for (int i = 0; i < 8; ++i) dst[t + i * 512] = src[t + i * 512];
    }
    __syncthreads();

    int wid = blockIdx.x * 8 + (t >> 6);
    if (wid >= NN / 16) return;                 // 3125 tiles
    int lane = t & 63;
    int r = wid * 16 + (lane & 15);
    int kg = (lane >> 4) << 3;

    s8v Ahi[4], Alo[4];
    const __half* ar = A + (size_t)r * D + kg;
    #pragma unroll
    for (int s = 0; s < 4; ++s) {
        s8v raw = *(const s8v*)(ar + s * 32);
        const __half* hp = (const __half*)&raw;
        #pragma unroll
        for (int j = 0; j < 8; ++j) {
            float a = __half2float(hp[j]);
            unsigned short h = f2bf(a);
            Ahi[s][j] = (short)h;
            Alo[s][j] = (short)f2bf(a - bf2f(h));
        }
    }

    int cb = lane & 15;
    int rb = wid * 16 + ((lane >> 4) << 2);
    #pragma unroll
    for (int nt = 0; nt < 8; ++nt) {
        f4v acc = {0.f, 0.f, 0.f, 0.f};
        #pragma unroll
        for (int s = 0; s < 4; ++s) {
            int off = ((nt * 4 + s) * 64 + lane) * 8;
            s8v bh = *(const s8v*)(Ws + off);
            s8v bl = *(const s8v*)(Ws + 16384 + off);
            acc = __builtin_amdgcn_mfma_f32_16x16x32_bf16(Ahi[s], bh, acc, 0, 0, 0);
            acc = __builtin_amdgcn_mfma_f32_16x16x32_bf16(Alo[s], bh, acc, 0, 0, 0);
            acc = __builtin_amdgcn_mfma_f32_16x16x32_bf16(Ahi[s], bl, acc, 0, 0, 0);
        }
        float bv = bias[nt * 16 + cb];
        __half* hp = H + (size_t)rb * D + nt * 16 + cb;
        #pragma unroll
        for (int q = 0; q < 4; ++q) {
            float v = fmaxf(acc[q] + bv, 0.f);
            hp[q * D] = __float2half(v);
        }
    }
}

// ---------------- aggregation: out = selfc*H[c] + sum snorm*H[srow] (fp16 in/out) ----------------
__global__ __launch_bounds__(256) void k_agg(const __half* __restrict__ Hm,
                                             const int* __restrict__ offs,
                                             const int* __restrict__ srow,
                                             const float* __restrict__ snorm,
                                             const float* __restrict__ selfc,
                                             __half* __restrict__ out) {
    int node = blockIdx.x * 8 + (threadIdx.x >> 5);
    if (node >= NN) return;
    int l4 = (threadIdx.x & 31) * 4;
    H4 sv = *(const H4*)(Hm + (size_t)node * D + l4);
    float2 s0 = __half22float2(sv.a), s1 = __half22float2(sv.b);
    float sc = selfc[node];
    float ax = sc * s0.x, ay = sc * s0.y, az = sc * s1.x, aw = sc * s1.y;
    int s = offs[node], e = offs[node + 1];
    int j = s;
    for (; j + 3 < e; j += 4) {
        float w0 = snorm[j],   w1 = snorm[j+1], w2 = snorm[j+2], w3 = snorm[j+3];
        int   r0 = srow[j],    r1 = srow[j+1],  r2 = srow[j+2],  r3 = srow[j+3];
        H4 v0 = *(const H4*)(Hm + (size_t)r0 * D + l4);
        H4 v1 = *(const H4*)(Hm + (size_t)r1 * D + l4);
        H4 v2 = *(const H4*)(Hm + (size_t)r2 * D + l4);
        H4 v3 = *(const H4*)(Hm + (size_t)r3 * D + l4);
        float2 p0 = __half22float2(v0.a), p1 = __half22float2(v0.b);
        float2 q0 = __half22float2(v1.a), q1 = __half22float2(v1.b);
        float2 u0 = __half22float2(v2.a), u1 = __half22float2(v2.b);
        float2 t0 = __half22float2(v3.a), t1 = __half22float2(v3.b);
        ax += w0 * p0.x + w1 * q0.x + w2 * u0.x + w3 * t0.x;
        ay += w0 * p0.y + w1 * q0.y + w2 * u0.y + w3 * t0.y;
        az += w0 * p1.x + w1 * q1.x + w2 * u1.x + w3 * t1.x;
        aw += w0 * p1.y + w1 * q1.y + w2 * u1.y + w3 * t1.y;
    }
    for (; j < e; ++j) {
        float w0 = snorm[j];
        H4 v0 = *(const H4*)(Hm + (size_t)srow[j] * D + l4);
        float2 p0 = __half22float2(v0.a), p1 = __half22float2(v0.b);
        ax += w0 * p0.x; ay += w0 * p0.y; az += w0 * p1.x; aw += w0 * p1.y;
    }
    H4 o;
    o.a = __floats2half2_rn(ax, ay);
    o.b = __floats2half2_rn(az, aw);
    *(H4*)(out + (size_t)node * D + l4) = o;
}

// ---------------- pooling + combined output GEMM ----------------

#define PCH 128
__global__ __launch_bounds__(128) void k_pool(const __half* __restrict__ Hm,
                                              const int* __restrict__ batch,
                                              float* __restrict__ psum,
                                              float* __restrict__ pcnt) {
    int t = threadIdx.x;
    int s = blockIdx.x * PCH;
    int e = min(s + PCH, NN);
    if (s >= NN) return;
    float acc = 0.f;
    int cur = batch[s];
    int cnt = 0;
    for (int n = s; n < e; ++n) {
        int g = batch[n];
        if (g != cur) {
            atomicAdd(&psum[cur * D + t], acc);
            if (t == 0) atomicAdd(&pcnt[cur], (float)cnt);
            acc = 0.f; cnt = 0; cur = g;
        }
        acc += __half2float(Hm[(size_t)n * D + t]);
        cnt++;
    }
    atomicAdd(&psum[cur * D + t], acc);
    if (t == 0) atomicAdd(&pcnt[cur], (float)cnt);
}

__global__ __launch_bounds__(64) void k_out(const float* __restrict__ psum,
                                            const float* __restrict__ pcnt,
                                            const float* __restrict__ Wcomb,
                                            const float* __restrict__ bcomb,
                                            float* __restrict__ outp) {
    __shared__ float prow[D];
    int g = blockIdx.x, t = threadIdx.x;
    float inv = 1.0f / fmaxf(pcnt[g], 1.0f);
    prow[t]      = psum[g * D + t] * inv;
    prow[t + 64] = psum[g * D + t + 64] * inv;
    __syncthreads();
    float acc = bcomb[t];
    for (int k = 0; k < D; ++k) acc += prow[k] * Wcomb[k * OD + t];
    outp[g * OD + t] = acc;
}

// ---------------- launch ----------------

extern "C" void kernel_launch(void* const* d_in, const int* in_sizes, int n_in,
                              void* d_out, int out_size, void* d_ws, size_t ws_size,
                              hipStream_t stream) {
    const float* x    = (const float*)d_in[0];
    const int*   ei   = (const int*)d_in[1];
    const int*   row  = ei;
    const int*   col  = ei + NE;
    const float* ew   = (const float*)d_in[2];
    const int*   batch= (const int*)d_in[3];
    const float* W1 = (const float*)d_in[4];  const float* b1 = (const float*)d_in[5];
    const float* W2 = (const float*)d_in[6];  const float* b2 = (const float*)d_in[7];
    const float* W3 = (const float*)d_in[8];  const float* b3 = (const float*)d_in[9];
    const float* W4 = (const float*)d_in[10]; const float* b4 = (const float*)d_in[11];
    const float* Wfc= (const float*)d_in[12]; const float* bfc= (const float*)d_in[13];

    float* ws = (float*)d_ws;
    float* dinv   = ws + 0;                  // 50048
    float* selfc  = ws + 50048;              // 50048
    int*   counts = (int*)(ws + 100096);     // 50176
    int*   offs   = (int*)(ws + 150272);     // 50176
    int*   rank   = (int*)(ws + 200448);     // 500000 (dead after fill2)
    float* snorm  = ws + 200448;             // aliases rank
    int*   srow   = (int*)(ws + 700448);     // 500000
    float* sew    = ws + 1200448;            // 500000
    __half* xh    = (__half*)(ws + 1700448); // 6.4M fp16
    __half* abuf  = (__half*)(ws + 4900448); // 6.4M fp16 (aggregated)
    __half* hbuf  = (__half*)(ws + 8100448); // 6.4M fp16 (layer out)
    float* psum   = ws + 11300448;           // 65536
    float* pcnt   = ws + 11365984;           // 512
    unsigned short* wpk = (unsigned short*)(ws + 11366496);  // 3*32768 ushort
    float* wcomb  = ws + 11415648;           // 8192
    float* bcomb  = ws + 11423840;           // 64
    int*   bsum   = (int*)(ws + 11423904);   // 256
    int*   bbase  = (int*)(ws + 11424160);   // 256

    const int TB = 256;
    int nblk = (NN + TB - 1) / TB;   // 196
    int eblk = (NE + TB - 1) / TB;   // 1954

    // setup + CSR build
    hipMemsetAsync(counts, 0, NN * sizeof(int), stream);
    hipMemsetAsync(psum, 0, NG * D * sizeof(float), stream);
    hipMemsetAsync(pcnt, 0, NG * sizeof(float), stream);
    k_pack_w<<<24, 256, 0, stream>>>(W1, W2, W3, wpk);
    k_comb_w<<<32, 256, 0, stream>>>(W4, Wfc, b4, bfc, wcomb, bcomb);
    k_x2h<<<(NN * D / 4 + 255) / 256, 256, 0, stream>>>(x, xh);
    k_count_rank<<<eblk, TB, 0, stream>>>(col, counts, rank);
    k_scan_blk<<<nblk, 256, 0, stream>>>(counts, offs, bsum);
    k_scan_top<<<1, 256, 0, stream>>>(bsum, bbase, nblk);
    k_scan_add<<<nblk, 256, 0, stream>>>(offs, bbase);
    k_fill2<<<eblk, TB, 0, stream>>>(row, col, ew, offs, rank, srow, sew);
    k_deg_csr<<<nblk, TB, 0, stream>>>(sew, offs, dinv, selfc);
    k_csr_norm<<<nblk, TB, 0, stream>>>(srow, sew, offs, dinv, snorm);

    const int GB = (NN / 16 + 7) / 8;    // 391 gemm blocks (8 waves each)
    const int AB = (NN + 7) / 8;         // 6250 agg blocks

    unsigned short* wp1 = wpk;
    unsigned short* wp2 = wpk + 32768;
    unsigned short* wp3 = wpk + 65536;

    // layers (aggregate-first: h_out = relu((Â h_in) W + b))
    k_agg<<<AB, 256, 0, stream>>>(xh,   offs, srow, snorm, selfc, abuf);
    k_gemm_mfma<<<GB, 512, 0, stream>>>(abuf, wp1, b1, hbuf);
    k_agg<<<AB, 256, 0, stream>>>(hbuf, offs, srow, snorm, selfc, abuf);
    k_gemm_mfma<<<GB, 512, 0, stream>>>(abuf, wp2, b2, hbuf);
    k_agg<<<AB, 256, 0, stream>>>(hbuf, offs, srow, snorm, selfc, abuf);
    k_gemm_mfma<<<GB, 512, 0, stream>>>(abuf, wp3, b3, hbuf);
    k_agg<<<AB, 256, 0, stream>>>(hbuf, offs, srow, snorm, selfc, abuf);

    // tail: out = pool(Â h3) @ (W4@Wfc) + (b4@Wfc + bfc)
    k_pool<<<(NN + PCH - 1) / PCH, 128, 0, stream>>>(abuf, batch, psum, pcnt);
    k_out<<<NG, 64, 0, stream>>>(psum, pcnt, wcomb, bcomb, (float*)d_out);
}

// Round 9
// 262.184 us; speedup vs baseline: 2.8582x; 1.0139x over previous
//
#include <hip/hip_runtime.h>
#include <hip/hip_fp16.h>

#define NN 50000
#define NE 500000
#define D  128
#define OD 64
#define NG 512

typedef __attribute__((ext_vector_type(8))) short s8v;    // 8 bf16/fp16 (16B)
typedef __attribute__((ext_vector_type(4))) float f4v;    // MFMA acc

__device__ inline unsigned short f2bf(float f) {
    unsigned u = __float_as_uint(f);
    unsigned r = (u + 0x7fffu + ((u >> 16) & 1u)) >> 16;   // RNE
    return (unsigned short)r;
}
__device__ inline float bf2f(unsigned short h) {
    return __uint_as_float(((unsigned)h) << 16);
}

struct H4 { __half2 a, b; };              // 4 fp16 = 8B
struct __align__(8) ER { int r; float w; };   // edge record: src row + weight/norm

// ---------------- fused setup: zero buffers, pack W1-3, comb W4@Wfc, x->fp16 ----------------
__global__ __launch_bounds__(256) void k_setup(const float* __restrict__ x,
                                               const float* __restrict__ w0,
                                               const float* __restrict__ w1,
                                               const float* __restrict__ w2,
                                               const float* __restrict__ W4,
                                               const float* __restrict__ Wfc,
                                               const float* __restrict__ b4,
                                               const float* __restrict__ bfc,
                                               int* __restrict__ counts,
                                               float* __restrict__ psum,   // psum|pcnt contiguous
                                               unsigned short* __restrict__ wpk,
                                               float* __restrict__ Wcomb,
                                               float* __restrict__ bcomb,
                                               __half* __restrict__ xh) {
    int b = blockIdx.x, t = threadIdx.x;
    if (b < 24) {                          // zero counts (50176 ints)
        for (int i = b * 256 + t; i < NN + 176; i += 24 * 256) counts[i] = 0;
    } else if (b < 56) {                   // zero psum+pcnt (66048 floats)
        for (int i = (b - 24) * 256 + t; i < NG * D + NG; i += 32 * 256) psum[i] = 0.f;
    } else if (b < 80) {                   // pack W1-3 into B-frag hi/lo layout
        int idx = b - 56;
        int layer = idx >> 3, chunk = idx & 7;
        const float* W = (layer == 0) ? w0 : (layer == 1) ? w1 : w2;
        unsigned short* hi = wpk + layer * 32768;
        unsigned short* lo = hi + 16384;
        for (int it = 0; it < 8; ++it) {
            int p = chunk * 2048 + it * 256 + t;
            int j = p & 7, lane = (p >> 3) & 63, s = (p >> 9) & 3, nt = p >> 11;
            int k = s * 32 + ((lane >> 4) << 3) + j;
            int n = nt * 16 + (lane & 15);
            float v = W[k * D + n];
            unsigned short h = f2bf(v);
            hi[p] = h;
            lo[p] = f2bf(v - bf2f(h));
        }
    } else if (b < 88) {                   // Wcomb = W4@Wfc ; bcomb = b4@Wfc + bfc
        int id = (b - 80) * 256 + t;       // 2048 threads
        #pragma unroll
        for (int q = 0; q < 4; ++q) {
            int p = id + q * 2048;         // 8192 outputs
            int k = p >> 6, n = p & 63;
            float s = 0.f;
            for (int j = 0; j < D; ++j) s += W4[k * D + j] * Wfc[j * OD + n];
            Wcomb[p] = s;
        }
        if (id < OD) {
            float s = bfc[id];
            for (int j = 0; j < D; ++j) s += b4[j] * Wfc[j * OD + id];
            bcomb[id] = s;
        }
    } else {                               // x -> fp16 (1.6M float4 groups)
        for (int i = (b - 88) * 256 + t; i < NN * D / 4; i += 1600 * 256) {
            float4 v = ((const float4*)x)[i];
            H4 o;
            o.a = __floats2half2_rn(v.x, v.y);
            o.b = __floats2half2_rn(v.z, v.w);
            ((H4*)xh)[i] = o;
        }
    }
}

// ---------------- CSR build ----------------
__global__ void k_count_rank(const int* __restrict__ col,
                             int* __restrict__ counts, int* __restrict__ rank) {
    int e = blockIdx.x * blockDim.x + threadIdx.x;
    if (e < NE) rank[e] = atomicAdd(&counts[col[e]], 1);
}

__global__ __launch_bounds__(256) void k_scan_blk(const int* __restrict__ counts,
                                                  int* __restrict__ offs,
                                                  int* __restrict__ bsum) {
    __shared__ int tmp[256];
    int b = blockIdx.x, t = threadIdx.x;
    int i = b * 256 + t;
    int v = (i < NN) ? counts[i] : 0;
    tmp[t] = v;
    __syncthreads();
    for (int st = 1; st < 256; st <<= 1) {
        int u = (t >= st) ? tmp[t - st] : 0;
        __syncthreads();
        tmp[t] += u;
        __syncthreads();
    }
    if (i < NN) offs[i] = tmp[t] - v;
    if (t == 255) bsum[b] = tmp[255];
}

__global__ __launch_bounds__(256) void k_scan_top(const int* __restrict__ bsum,
                                                  int* __restrict__ bbase, int nb) {
    __shared__ int tmp[256];
    int t = threadIdx.x;
    int v = (t < nb) ? bsum[t] : 0;
    tmp[t] = v;
    __syncthreads();
    for (int st = 1; st < 256; st <<= 1) {
        int u = (t >= st) ? tmp[t - st] : 0;
        __syncthreads();
        tmp[t] += u;
        __syncthreads();
    }
    if (t < nb) bbase[t] = tmp[t] - v;
}

__global__ __launch_bounds__(256) void k_scan_add(int* __restrict__ offs,
                                                  const int* __restrict__ bbase) {
    int b = blockIdx.x, t = threadIdx.x;
    int i = b * 256 + t;
    if (i < NN) offs[i] += bbase[b];
    if (b == 0 && t == 0) offs[NN] = NE;
}

__global__ void k_fill2(const int* __restrict__ row, const int* __restrict__ col,
                        const float* __restrict__ ew, const int* __restrict__ offs,
                        const int* __restrict__ rank, ER* __restrict__ esr) {
    int e = blockIdx.x * blockDim.x + threadIdx.x;
    if (e < NE) {
        ER v;
        v.r = row[e];
        v.w = ew[e];
        esr[offs[col[e]] + rank[e]] = v;   // one 8B scattered store
    }
}

__global__ void k_deg_csr(const ER* __restrict__ esr, const int* __restrict__ offs,
                          float* __restrict__ dinv, float* __restrict__ selfc) {
    int i = blockIdx.x * blockDim.x + threadIdx.x;
    if (i < NN) {
        float s = 1.0f;
        int a = offs[i], b = offs[i + 1];
        for (int j = a; j < b; ++j) s += esr[j].w;
        float r = rsqrtf(s);
        dinv[i] = r;
        selfc[i] = r * r;
    }
}

// in-place: esr[j].w = dinv[c] * ew * dinv[srow]
__global__ void k_csr_norm(ER* __restrict__ esr, const int* __restrict__ offs,
                           const float* __restrict__ dinv) {
    int i = blockIdx.x * blockDim.x + threadIdx.x;
    if (i < NN) {
        float di = dinv[i];
        int a = offs[i], b = offs[i + 1];
        for (int j = a; j < b; ++j) {
            ER v = esr[j];
            v.w = di * v.w * dinv[v.r];
            esr[j] = v;
        }
    }
}

// ---------------- MFMA GEMM: H(fp16) = relu(A @ W + b) (split-bf16, 3 terms) ----------------
__global__ __launch_bounds__(512) void k_gemm_mfma(const __half* __restrict__ A,
                                                   const unsigned short* __restrict__ Wl,
                                                   const float* __restrict__ bias,
                                                   __half* __restrict__ H) {
    __shared__ unsigned short Ws[32768];       // hi[16384] | lo[16384] = 64 KB
    int t = threadIdx.x;
    {
        const float4* src = (const float4*)Wl;
        float4* dst = (float4*)Ws;
        #pragma unroll
        for (int i = 0; i < 8; ++i) dst[t + i * 512] = src[t + i * 512];
    }
    __syncthreads();

    int wid = blockIdx.x * 8 + (t >> 6);
    if (wid >= NN / 16) return;                 // 3125 tiles
    int lane = t & 63;
    int r = wid * 16 + (lane & 15);
    int kg = (lane >> 4) << 3;

    s8v Ahi[4], Alo[4];
    const __half* ar = A + (size_t)r * D + kg;
    #pragma unroll
    for (int s = 0; s < 4; ++s) {
        s8v raw = *(const s8v*)(ar + s * 32);
        const __half* hp = (const __half*)&raw;
        #pragma unroll
        for (int j = 0; j < 8; ++j) {
            float a = __half2float(hp[j]);
            unsigned short h = f2bf(a);
            Ahi[s][j] = (short)h;
            Alo[s][j] = (short)f2bf(a - bf2f(h));
        }
    }

    int cb = lane & 15;
    int rb = wid * 16 + ((lane >> 4) << 2);
    #pragma unroll
    for (int nt = 0; nt < 8; ++nt) {
        f4v acc = {0.f, 0.f, 0.f, 0.f};
        #pragma unroll
        for (int s = 0; s < 4; ++s) {
            int off = ((nt * 4 + s) * 64 + lane) * 8;
            s8v bh = *(const s8v*)(Ws + off);
            s8v bl = *(const s8v*)(Ws + 16384 + off);
            acc = __builtin_amdgcn_mfma_f32_16x16x32_bf16(Ahi[s], bh, acc, 0, 0, 0);
            acc = __builtin_amdgcn_mfma_f32_16x16x32_bf16(Alo[s], bh, acc, 0, 0, 0);
            acc = __builtin_amdgcn_mfma_f32_16x16x32_bf16(Ahi[s], bl, acc, 0, 0, 0);
        }
        float bv = bias[nt * 16 + cb];
        __half* hp = H + (size_t)rb * D + nt * 16 + cb;
        #pragma unroll
        for (int q = 0; q < 4; ++q) {
            float v = fmaxf(acc[q] + bv, 0.f);
            hp[q * D] = __float2half(v);
        }
    }
}

// ---------------- aggregation: out = selfc*H[c] + sum w*H[r] (fp16 in/out, 8-deep ILP) ----------------
__global__ __launch_bounds__(256) void k_agg(const __half* __restrict__ Hm,
                                             const int* __restrict__ offs,
                                             const ER* __restrict__ esr,
                                             const float* __restrict__ selfc,
                                             __half* __restrict__ out) {
    int node = blockIdx.x * 8 + (threadIdx.x >> 5);
    if (node >= NN) return;
    int l4 = (threadIdx.x & 31) * 4;
    H4 sv = *(const H4*)(Hm + (size_t)node * D + l4);
    float2 s0 = __half22float2(sv.a), s1 = __half22float2(sv.b);
    float sc = selfc[node];
    float ax = sc * s0.x, ay = sc * s0.y, az = sc * s1.x, aw = sc * s1.y;
    int s = offs[node], e = offs[node + 1];
    int j = s;
    for (; j + 8 <= e; j += 8) {
        ER er[8];
        #pragma unroll
        for (int q = 0; q < 8; ++q) er[q] = esr[j + q];
        H4 v[8];
        #pragma unroll
        for (int q = 0; q < 8; ++q) v[q] = *(const H4*)(Hm + (size_t)er[q].r * D + l4);
        #pragma unroll
        for (int q = 0; q < 8; ++q) {
            float w = er[q].w;
            float2 p0 = __half22float2(v[q].a), p1 = __half22float2(v[q].b);
            ax += w * p0.x; ay += w * p0.y; az += w * p1.x; aw += w * p1.y;
        }
    }
    for (; j < e; ++j) {
        ER er = esr[j];
        H4 v0 = *(const H4*)(Hm + (size_t)er.r * D + l4);
        float2 p0 = __half22float2(v0.a), p1 = __half22float2(v0.b);
        ax += er.w * p0.x; ay += er.w * p0.y; az += er.w * p1.x; aw += er.w * p1.y;
    }
    H4 o;
    o.a = __floats2half2_rn(ax, ay);
    o.b = __floats2half2_rn(az, aw);
    *(H4*)(out + (size_t)node * D + l4) = o;
}

// ---------------- pooling + combined output GEMM ----------------

#define PCH 128
__global__ __launch_bounds__(128) void k_pool(const __half* __restrict__ Hm,
                                              const int* __restrict__ batch,
                                              float* __restrict__ psum,
                                              float* __restrict__ pcnt) {
    int t = threadIdx.x;
    int s = blockIdx.x * PCH;
    int e = min(s + PCH, NN);
    if (s >= NN) return;
    float acc = 0.f;
    int cur = batch[s];
    int cnt = 0;
    for (int n = s; n < e; ++n) {
        int g = batch[n];
        if (g != cur) {
            atomicAdd(&psum[cur * D + t], acc);
            if (t == 0) atomicAdd(&pcnt[cur], (float)cnt);
            acc = 0.f; cnt = 0; cur = g;
        }
        acc += __half2float(Hm[(size_t)n * D + t]);
        cnt++;
    }
    atomicAdd(&psum[cur * D + t], acc);
    if (t == 0) atomicAdd(&pcnt[cur], (float)cnt);
}

__global__ __launch_bounds__(64) void k_out(const float* __restrict__ psum,
                                            const float* __restrict__ pcnt,
                                            const float* __restrict__ Wcomb,
                                            const float* __restrict__ bcomb,
                                            float* __restrict__ outp) {
    __shared__ float prow[D];
    int g = blockIdx.x, t = threadIdx.x;
    float inv = 1.0f / fmaxf(pcnt[g], 1.0f);
    prow[t]      = psum[g * D + t] * inv;
    prow[t + 64] = psum[g * D + t + 64] * inv;
    __syncthreads();
    float acc = bcomb[t];
    for (int k = 0; k < D; ++k) acc += prow[k] * Wcomb[k * OD + t];
    outp[g * OD + t] = acc;
}

// ---------------- launch ----------------

extern "C" void kernel_launch(void* const* d_in, const int* in_sizes, int n_in,
                              void* d_out, int out_size, void* d_ws, size_t ws_size,
                              hipStream_t stream) {
    const float* x    = (const float*)d_in[0];
    const int*   ei   = (const int*)d_in[1];
    const int*   row  = ei;
    const int*   col  = ei + NE;
    const float* ew   = (const float*)d_in[2];
    const int*   batch= (const int*)d_in[3];
    const float* W1 = (const float*)d_in[4];  const float* b1 = (const float*)d_in[5];
    const float* W2 = (const float*)d_in[6];  const float* b2 = (const float*)d_in[7];
    const float* W3 = (const float*)d_in[8];  const float* b3 = (const float*)d_in[9];
    const float* W4 = (const float*)d_in[10]; const float* b4 = (const float*)d_in[11];
    const float* Wfc= (const float*)d_in[12]; const float* bfc= (const float*)d_in[13];

    float* ws = (float*)d_ws;
    float* dinv   = ws + 0;                  // 50048
    float* selfc  = ws + 50048;              // 50048
    int*   counts = (int*)(ws + 100096);     // 50176
    int*   offs   = (int*)(ws + 150272);     // 50176
    int*   rank   = (int*)(ws + 200448);     // 500000
    ER*    esr    = (ER*)(ws + 700448);      // 500000 * 8B = 1000000 floats
    __half* xh    = (__half*)(ws + 1700448); // 6.4M fp16
    __half* abuf  = (__half*)(ws + 4900448); // 6.4M fp16
    __half* hbuf  = (__half*)(ws + 8100448); // 6.4M fp16
    float* psum   = ws + 11300448;           // 65536 (+pcnt contiguous)
    float* pcnt   = ws + 11365984;           // 512
    unsigned short* wpk = (unsigned short*)(ws + 11366496);  // 3*32768 ushort
    float* wcomb  = ws + 11415648;           // 8192
    float* bcomb  = ws + 11423840;           // 64
    int*   bsum   = (int*)(ws + 11423904);   // 256
    int*   bbase  = (int*)(ws + 11424160);   // 256

    const int TB = 256;
    int nblk = (NN + TB - 1) / TB;   // 196
    int eblk = (NE + TB - 1) / TB;   // 1954

    // fused setup (zeros + weight prep + x->fp16), then CSR build
    k_setup<<<1688, 256, 0, stream>>>(x, W1, W2, W3, W4, Wfc, b4, bfc,
                                      counts, psum, wpk, wcomb, bcomb, xh);
    k_count_rank<<<eblk, TB, 0, stream>>>(col, counts, rank);
    k_scan_blk<<<nblk, 256, 0, stream>>>(counts, offs, bsum);
    k_scan_top<<<1, 256, 0, stream>>>(bsum, bbase, nblk);
    k_scan_add<<<nblk, 256, 0, stream>>>(offs, bbase);
    k_fill2<<<eblk, TB, 0, stream>>>(row, col, ew, offs, rank, esr);
    k_deg_csr<<<nblk, TB, 0, stream>>>(esr, offs, dinv, selfc);
    k_csr_norm<<<nblk, TB, 0, stream>>>(esr, offs, dinv);

    const int GB = (NN / 16 + 7) / 8;    // 391 gemm blocks (8 waves each)
    const int AB = (NN + 7) / 8;         // 6250 agg blocks

    unsigned short* wp1 = wpk;
    unsigned short* wp2 = wpk + 32768;
    unsigned short* wp3 = wpk + 65536;

    // layers (aggregate-first: h_out = relu((Â h_in) W + b))
    k_agg<<<AB, 256, 0, stream>>>(xh,   offs, esr, selfc, abuf);
    k_gemm_mfma<<<GB, 512, 0, stream>>>(abuf, wp1, b1, hbuf);
    k_agg<<<AB, 256, 0, stream>>>(hbuf, offs, esr, selfc, abuf);
    k_gemm_mfma<<<GB, 512, 0, stream>>>(abuf, wp2, b2, hbuf);
    k_agg<<<AB, 256, 0, stream>>>(hbuf, offs, esr, selfc, abuf);
    k_gemm_mfma<<<GB, 512, 0, stream>>>(abuf, wp3, b3, hbuf);
    k_agg<<<AB, 256, 0, stream>>>(hbuf, offs, esr, selfc, abuf);

    // tail: out = pool(Â h3) @ (W4@Wfc) + (b4@Wfc + bfc)
    k_pool<<<(NN + PCH - 1) / PCH, 128, 0, stream>>>(abuf, batch, psum, pcnt);
    k_out<<<NG, 64, 0, stream>>>(psum, pcnt, wcomb, bcomb, (float*)d_out);
}

// Round 10
// 241.465 us; speedup vs baseline: 3.1035x; 1.0858x over previous
//
#include <hip/hip_runtime.h>
#include <hip/hip_fp16.h>

#define NN 50000
#define NE 500000
#define D  128
#define OD 64
#define NG 512

typedef __attribute__((ext_vector_type(8))) short s8v;    // 8 bf16/fp16 (16B)
typedef __attribute__((ext_vector_type(4))) float f4v;    // MFMA acc

__device__ inline unsigned short f2bf(float f) {
    unsigned u = __float_as_uint(f);
    unsigned r = (u + 0x7fffu + ((u >> 16) & 1u)) >> 16;   // RNE
    return (unsigned short)r;
}
__device__ inline float bf2f(unsigned short h) {
    return __uint_as_float(((unsigned)h) << 16);
}

struct H4 { __half2 a, b; };              // 4 fp16 = 8B
struct __align__(8) ER { int r; float w; };   // edge record: src row + weight/norm

// ---------------- fused setup: zero counts, pack W1-3, comb W4@Wfc, x->fp16 ----------------
__global__ __launch_bounds__(256) void k_setup(const float* __restrict__ x,
                                               const float* __restrict__ w0,
                                               const float* __restrict__ w1,
                                               const float* __restrict__ w2,
                                               const float* __restrict__ W4,
                                               const float* __restrict__ Wfc,
                                               const float* __restrict__ b4,
                                               const float* __restrict__ bfc,
                                               int* __restrict__ counts,
                                               unsigned short* __restrict__ wpk,
                                               float* __restrict__ Wcomb,
                                               float* __restrict__ bcomb,
                                               __half* __restrict__ xh) {
    int b = blockIdx.x, t = threadIdx.x;
    if (b < 24) {                          // zero counts (50176 ints)
        for (int i = b * 256 + t; i < NN + 176; i += 24 * 256) counts[i] = 0;
    } else if (b < 48) {                   // pack W1-3 into B-frag hi/lo layout
        int idx = b - 24;
        int layer = idx >> 3, chunk = idx & 7;
        const float* W = (layer == 0) ? w0 : (layer == 1) ? w1 : w2;
        unsigned short* hi = wpk + layer * 32768;
        unsigned short* lo = hi + 16384;
        for (int it = 0; it < 8; ++it) {
            int p = chunk * 2048 + it * 256 + t;
            int j = p & 7, lane = (p >> 3) & 63, s = (p >> 9) & 3, nt = p >> 11;
            int k = s * 32 + ((lane >> 4) << 3) + j;
            int n = nt * 16 + (lane & 15);
            float v = W[k * D + n];
            unsigned short h = f2bf(v);
            hi[p] = h;
            lo[p] = f2bf(v - bf2f(h));
        }
    } else if (b < 56) {                   // Wcomb = W4@Wfc ; bcomb = b4@Wfc + bfc
        int id = (b - 48) * 256 + t;       // 2048 threads
        #pragma unroll
        for (int q = 0; q < 4; ++q) {
            int p = id + q * 2048;         // 8192 outputs
            int k = p >> 6, n = p & 63;
            float s = 0.f;
            for (int j = 0; j < D; ++j) s += W4[k * D + j] * Wfc[j * OD + n];
            Wcomb[p] = s;
        }
        if (id < OD) {
            float s = bfc[id];
            for (int j = 0; j < D; ++j) s += b4[j] * Wfc[j * OD + id];
            bcomb[id] = s;
        }
    } else {                               // x -> fp16 (1.6M float4 groups)
        for (int i = (b - 56) * 256 + t; i < NN * D / 4; i += 1600 * 256) {
            float4 v = ((const float4*)x)[i];
            H4 o;
            o.a = __floats2half2_rn(v.x, v.y);
            o.b = __floats2half2_rn(v.z, v.w);
            ((H4*)xh)[i] = o;
        }
    }
}

// ---------------- CSR build ----------------
__global__ void k_count_rank(const int* __restrict__ col,
                             int* __restrict__ counts, int* __restrict__ rank) {
    int e = blockIdx.x * blockDim.x + threadIdx.x;
    if (e < NE) rank[e] = atomicAdd(&counts[col[e]], 1);
}

__global__ __launch_bounds__(256) void k_scan_blk(const int* __restrict__ counts,
                                                  int* __restrict__ offs,
                                                  int* __restrict__ bsum) {
    __shared__ int tmp[256];
    int b = blockIdx.x, t = threadIdx.x;
    int i = b * 256 + t;
    int v = (i < NN) ? counts[i] : 0;
    tmp[t] = v;
    __syncthreads();
    for (int st = 1; st < 256; st <<= 1) {
        int u = (t >= st) ? tmp[t - st] : 0;
        __syncthreads();
        tmp[t] += u;
        __syncthreads();
    }
    if (i < NN) offs[i] = tmp[t] - v;
    if (t == 255) bsum[b] = tmp[255];
}

__global__ __launch_bounds__(256) void k_scan_top(const int* __restrict__ bsum,
                                                  int* __restrict__ bbase, int nb) {
    __shared__ int tmp[256];
    int t = threadIdx.x;
    int v = (t < nb) ? bsum[t] : 0;
    tmp[t] = v;
    __syncthreads();
    for (int st = 1; st < 256; st <<= 1) {
        int u = (t >= st) ? tmp[t - st] : 0;
        __syncthreads();
        tmp[t] += u;
        __syncthreads();
    }
    if (t < nb) bbase[t] = tmp[t] - v;
}

__global__ __launch_bounds__(256) void k_scan_add(int* __restrict__ offs,
                                                  const int* __restrict__ bbase) {
    int b = blockIdx.x, t = threadIdx.x;
    int i = b * 256 + t;
    if (i < NN) offs[i] += bbase[b];
    if (b == 0 && t == 0) offs[NN] = NE;
}

__global__ void k_fill2(const int* __restrict__ row, const int* __restrict__ col,
                        const float* __restrict__ ew, const int* __restrict__ offs,
                        const int* __restrict__ rank, ER* __restrict__ esr) {
    int e = blockIdx.x * blockDim.x + threadIdx.x;
    if (e < NE) {
        ER v;
        v.r = row[e];
        v.w = ew[e];
        esr[offs[col[e]] + rank[e]] = v;   // one 8B scattered store
    }
}

__global__ void k_deg_csr(const ER* __restrict__ esr, const int* __restrict__ offs,
                          float* __restrict__ dinv, float* __restrict__ selfc) {
    int i = blockIdx.x * blockDim.x + threadIdx.x;
    if (i < NN) {
        float s = 1.0f;
        int a = offs[i], b = offs[i + 1];
        for (int j = a; j < b; ++j) s += esr[j].w;
        float r = rsqrtf(s);
        dinv[i] = r;
        selfc[i] = r * r;
    }
}

// in-place: esr[j].w = dinv[c] * ew * dinv[srow]
__global__ void k_csr_norm(ER* __restrict__ esr, const int* __restrict__ offs,
                           const float* __restrict__ dinv) {
    int i = blockIdx.x * blockDim.x + threadIdx.x;
    if (i < NN) {
        float di = dinv[i];
        int a = offs[i], b = offs[i + 1];
        for (int j = a; j < b; ++j) {
            ER v = esr[j];
            v.w = di * v.w * dinv[v.r];
            esr[j] = v;
        }
    }
}

// ---------------- MFMA GEMM: H(fp16) = relu(A @ W + b) (split-bf16, 3 terms) ----------------
__global__ __launch_bounds__(512) void k_gemm_mfma(const __half* __restrict__ A,
                                                   const unsigned short* __restrict__ Wl,
                                                   const float* __restrict__ bias,
                                                   __half* __restrict__ H) {
    __shared__ unsigned short Ws[32768];       // hi[16384] | lo[16384] = 64 KB
    int t = threadIdx.x;
    {
        const float4* src = (const float4*)Wl;
        float4* dst = (float4*)Ws;
        #pragma unroll
        for (int i = 0; i < 8; ++i) dst[t + i * 512] = src[t + i * 512];
    }
    __syncthreads();

    int wid = blockIdx.x * 8 + (t >> 6);
    if (wid >= NN / 16) return;                 // 3125 tiles
    int lane = t & 63;
    int r = wid * 16 + (lane & 15);
    int kg = (lane >> 4) << 3;

    s8v Ahi[4], Alo[4];
    const __half* ar = A + (size_t)r * D + kg;
    #pragma unroll
    for (int s = 0; s < 4; ++s) {
        s8v raw = *(const s8v*)(ar + s * 32);
        const __half* hp = (const __half*)&raw;
        #pragma unroll
        for (int j = 0; j < 8; ++j) {
            float a = __half2float(hp[j]);
            unsigned short h = f2bf(a);
            Ahi[s][j] = (short)h;
            Alo[s][j] = (short)f2bf(a - bf2f(h));
        }
    }

    int cb = lane & 15;
    int rb = wid * 16 + ((lane >> 4) << 2);
    #pragma unroll
    for (int nt = 0; nt < 8; ++nt) {
        f4v acc = {0.f, 0.f, 0.f, 0.f};
        #pragma unroll
        for (int s = 0; s < 4; ++s) {
            int off = ((nt * 4 + s) * 64 + lane) * 8;
            s8v bh = *(const s8v*)(Ws + off);
            s8v bl = *(const s8v*)(Ws + 16384 + off);
            acc = __builtin_amdgcn_mfma_f32_16x16x32_bf16(Ahi[s], bh, acc, 0, 0, 0);
            acc = __builtin_amdgcn_mfma_f32_16x16x32_bf16(Alo[s], bh, acc, 0, 0, 0);
            acc = __builtin_amdgcn_mfma_f32_16x16x32_bf16(Ahi[s], bl, acc, 0, 0, 0);
        }
        float bv = bias[nt * 16 + cb];
        __half* hp = H + (size_t)rb * D + nt * 16 + cb;
        #pragma unroll
        for (int q = 0; q < 4; ++q) {
            float v = fmaxf(acc[q] + bv, 0.f);
            hp[q * D] = __float2half(v);
        }
    }
}

// ---------------- aggregation: out = selfc*H[c] + sum w*H[r] (fp16 in/out, 8-deep ILP) ----------------
__global__ __launch_bounds__(256) void k_agg(const __half* __restrict__ Hm,
                                             const int* __restrict__ offs,
                                             const ER* __restrict__ esr,
                                             const float* __restrict__ selfc,
                                             __half* __restrict__ out) {
    int node = blockIdx.x * 8 + (threadIdx.x >> 5);
    if (node >= NN) return;
    int l4 = (threadIdx.x & 31) * 4;
    H4 sv = *(const H4*)(Hm + (size_t)node * D + l4);
    float2 s0 = __half22float2(sv.a), s1 = __half22float2(sv.b);
    float sc = selfc[node];
    float ax = sc * s0.x, ay = sc * s0.y, az = sc * s1.x, aw = sc * s1.y;
    int s = offs[node], e = offs[node + 1];
    int j = s;
    for (; j + 8 <= e; j += 8) {
        ER er[8];
        #pragma unroll
        for (int q = 0; q < 8; ++q) er[q] = esr[j + q];
        H4 v[8];
        #pragma unroll
        for (int q = 0; q < 8; ++q) v[q] = *(const H4*)(Hm + (size_t)er[q].r * D + l4);
        #pragma unroll
        for (int q = 0; q < 8; ++q) {
            float w = er[q].w;
            float2 p0 = __half22float2(v[q].a), p1 = __half22float2(v[q].b);
            ax += w * p0.x; ay += w * p0.y; az += w * p1.x; aw += w * p1.y;
        }
    }
    for (; j < e; ++j) {
        ER er = esr[j];
        H4 v0 = *(const H4*)(Hm + (size_t)er.r * D + l4);
        float2 p0 = __half22float2(v0.a), p1 = __half22float2(v0.b);
        ax += er.w * p0.x; ay += er.w * p0.y; az += er.w * p1.x; aw += er.w * p1.y;
    }
    H4 o;
    o.a = __floats2half2_rn(ax, ay);
    o.b = __floats2half2_rn(az, aw);
    *(H4*)(out + (size_t)node * D + l4) = o;
}

// ---------------- fused mean-pool + output GEMM: one block per graph ----------------
// batch is sorted; block g binary-searches its node range, branch-free sums it,
// then computes out[g] = pooled @ Wcomb + bcomb from LDS.
__global__ __launch_bounds__(128) void k_poolout(const __half* __restrict__ Hm,
                                                 const int* __restrict__ batch,
                                                 const float* __restrict__ Wcomb,
                                                 const float* __restrict__ bcomb,
                                                 float* __restrict__ outp) {
    __shared__ float prow[D];
    __shared__ int seb[2];
    int g = blockIdx.x, t = threadIdx.x;
    if (t < 2) {
        int target = g + t;
        int lo = 0, hi = NN;
        while (lo < hi) {
            int mid = (lo + hi) >> 1;
            if (batch[mid] < target) lo = mid + 1; else hi = mid;
        }
        seb[t] = lo;
    }
    __syncthreads();
    int s = seb[0], e = seb[1];
    float a0 = 0.f, a1 = 0.f, a2 = 0.f, a3 = 0.f;
    int n = s;
    for (; n + 4 <= e; n += 4) {
        a0 += __half2float(Hm[(size_t)(n + 0) * D + t]);
        a1 += __half2float(Hm[(size_t)(n + 1) * D + t]);
        a2 += __half2float(Hm[(size_t)(n + 2) * D + t]);
        a3 += __half2float(Hm[(size_t)(n + 3) * D + t]);
    }
    for (; n < e; ++n) a0 += __half2float(Hm[(size_t)n * D + t]);
    float inv = 1.0f / (float)max(e - s, 1);
    prow[t] = (a0 + a1 + a2 + a3) * inv;
    __syncthreads();
    if (t < OD) {
        float acc = bcomb[t];
        #pragma unroll 4
        for (int k = 0; k < D; ++k) acc += prow[k] * Wcomb[k * OD + t];
        outp[g * OD + t] = acc;
    }
}

// ---------------- launch ----------------

extern "C" void kernel_launch(void* const* d_in, const int* in_sizes, int n_in,
                              void* d_out, int out_size, void* d_ws, size_t ws_size,
                              hipStream_t stream) {
    const float* x    = (const float*)d_in[0];
    const int*   ei   = (const int*)d_in[1];
    const int*   row  = ei;
    const int*   col  = ei + NE;
    const float* ew   = (const float*)d_in[2];
    const int*   batch= (const int*)d_in[3];
    const float* W1 = (const float*)d_in[4];  const float* b1 = (const float*)d_in[5];
    const float* W2 = (const float*)d_in[6];  const float* b2 = (const float*)d_in[7];
    const float* W3 = (const float*)d_in[8];  const float* b3 = (const float*)d_in[9];
    const float* W4 = (const float*)d_in[10]; const float* b4 = (const float*)d_in[11];
    const float* Wfc= (const float*)d_in[12]; const float* bfc= (const float*)d_in[13];

    float* ws = (float*)d_ws;
    float* dinv   = ws + 0;                  // 50048
    float* selfc  = ws + 50048;              // 50048
    int*   counts = (int*)(ws + 100096);     // 50176
    int*   offs   = (int*)(ws + 150272);     // 50176
    int*   rank   = (int*)(ws + 200448);     // 500000
    ER*    esr    = (ER*)(ws + 700448);      // 500000 * 8B
    __half* xh    = (__half*)(ws + 1700448); // 6.4M fp16
    __half* abuf  = (__half*)(ws + 4900448); // 6.4M fp16
    __half* hbuf  = (__half*)(ws + 8100448); // 6.4M fp16
    unsigned short* wpk = (unsigned short*)(ws + 11300448);  // 3*32768 ushort
    float* wcomb  = ws + 11349600;           // 8192
    float* bcomb  = ws + 11357792;           // 64
    int*   bsum   = (int*)(ws + 11357856);   // 256
    int*   bbase  = (int*)(ws + 11358112);   // 256

    const int TB = 256;
    int nblk = (NN + TB - 1) / TB;   // 196
    int eblk = (NE + TB - 1) / TB;   // 1954

    // fused setup (zero counts + weight prep + x->fp16), then CSR build
    k_setup<<<1656, 256, 0, stream>>>(x, W1, W2, W3, W4, Wfc, b4, bfc,
                                      counts, wpk, wcomb, bcomb, xh);
    k_count_rank<<<eblk, TB, 0, stream>>>(col, counts, rank);
    k_scan_blk<<<nblk, 256, 0, stream>>>(counts, offs, bsum);
    k_scan_top<<<1, 256, 0, stream>>>(bsum, bbase, nblk);
    k_scan_add<<<nblk, 256, 0, stream>>>(offs, bbase);
    k_fill2<<<eblk, TB, 0, stream>>>(row, col, ew, offs, rank, esr);
    k_deg_csr<<<nblk, TB, 0, stream>>>(esr, offs, dinv, selfc);
    k_csr_norm<<<nblk, TB, 0, stream>>>(esr, offs, dinv);

    const int GB = (NN / 16 + 7) / 8;    // 391 gemm blocks (8 waves each)
    const int AB = (NN + 7) / 8;         // 6250 agg blocks

    unsigned short* wp1 = wpk;
    unsigned short* wp2 = wpk + 32768;
    unsigned short* wp3 = wpk + 65536;

    // layers (aggregate-first: h_out = relu((Â h_in) W + b))
    k_agg<<<AB, 256, 0, stream>>>(xh,   offs, esr, selfc, abuf);
    k_gemm_mfma<<<GB, 512, 0, stream>>>(abuf, wp1, b1, hbuf);
    k_agg<<<AB, 256, 0, stream>>>(hbuf, offs, esr, selfc, abuf);
    k_gemm_mfma<<<GB, 512, 0, stream>>>(abuf, wp2, b2, hbuf);
    k_agg<<<AB, 256, 0, stream>>>(hbuf, offs, esr, selfc, abuf);
    k_gemm_mfma<<<GB, 512, 0, stream>>>(abuf, wp3, b3, hbuf);
    k_agg<<<AB, 256, 0, stream>>>(hbuf, offs, esr, selfc, abuf);

    // tail: fused mean-pool + (W4@Wfc) GEMM
    k_poolout<<<NG, 128, 0, stream>>>(abuf, batch, wcomb, bcomb, (float*)d_out);
}